// Round 3
// baseline (958.120 us; speedup 1.0000x reference)
//
#include <hip/hip_runtime.h>

#define NN 2048
#define NH 4
#define DD 64
#define FIN 128
#define NB 4

// ws layout (f32):
//   h_ws [B][H][N][D]  @ 0        : 8 MB
//   ei   [B][H][N]     @ 8388608  : 128 KB
//   ej   [B][H][N]     @ 8519680  : 128 KB

__global__ __launch_bounds__(256)
void k_hproj(const float* __restrict__ x, const float* __restrict__ W,
             const float* __restrict__ a,
             float* __restrict__ h_ws, float* __restrict__ ei_ws, float* __restrict__ ej_ws) {
    const int ng   = blockIdx.x;          // 0..8191 global node
    const int b    = ng >> 11;
    const int n    = ng & 2047;
    const int c    = threadIdx.x;         // 0..255 output column
    const int head = c >> 6;
    const int d    = c & 63;
    const int lane = threadIdx.x & 63;    // == d

    const float* xr = x + (size_t)ng * FIN;
    float acc = 0.f;
    #pragma unroll
    for (int kc = 0; kc < 32; ++kc) {
        const float4 xv = *(const float4*)(xr + kc * 4);
        acc += xv.x * W[(kc * 4 + 0) * 256 + c];
        acc += xv.y * W[(kc * 4 + 1) * 256 + c];
        acc += xv.z * W[(kc * 4 + 2) * 256 + c];
        acc += xv.w * W[(kc * 4 + 3) * 256 + c];
    }
    h_ws[((size_t)(b * NH + head) * NN + n) * DD + d] = acc;

    float eip = acc * a[d];
    float ejp = acc * a[64 + d];
    #pragma unroll
    for (int off = 1; off < 64; off <<= 1) {
        eip += __shfl_xor(eip, off);
        ejp += __shfl_xor(ejp, off);
    }
    if (lane == 0) {
        ei_ws[(size_t)(b * NH + head) * NN + n] = eip;
        ej_ws[(size_t)(b * NH + head) * NN + n] = ejp;
    }
}

// grid (ib=128, b=4), block 256. wave = head; wave handles rows [ib*16, ib*16+16).
// lanes = d for O-accumulation; register tile of 64 h-rows reused across 16 i.
__global__ __launch_bounds__(256)
void k_attn_valu(const int* __restrict__ adj, const float* __restrict__ h_ws,
                 const float* __restrict__ ei_ws, const float* __restrict__ ej_ws,
                 float* __restrict__ out) {
    const int ib   = blockIdx.x;
    const int b    = blockIdx.y;
    const int tid  = threadIdx.x;
    const int hd   = tid >> 6;
    const int lane = tid & 63;
    const int i0   = ib * 16;

    const float* hrow = h_ws + (size_t)(b * NH + hd) * NN * DD;
    const float* ejr  = ej_ws + (size_t)(b * NH + hd) * NN;
    const int*   adjr = adj + ((size_t)(b * NN + i0)) * NN;

    float eiv[16];
    #pragma unroll
    for (int ii = 0; ii < 16; ++ii)
        eiv[ii] = ei_ws[(size_t)(b * NH + hd) * NN + i0 + ii];

    float O[16], L[16];
    #pragma unroll
    for (int ii = 0; ii < 16; ++ii) { O[ii] = 0.f; L[ii] = 0.f; }

    for (int jb = 0; jb < 32; ++jb) {
        const int j = jb * 64 + lane;
        const float ejv = ejr[j];

        float p[16];
        #pragma unroll
        for (int ii = 0; ii < 16; ++ii) {
            const int av = adjr[(size_t)ii * NN + j];
            float e = eiv[ii] + ejv;
            e = (e >= 0.f) ? e : 0.2f * e;
            const float pp = (av != 0) ? __expf(e) : 0.f;
            p[ii] = pp;
            L[ii] += pp;
        }

        float hreg[64];
        #pragma unroll
        for (int jj = 0; jj < 64; ++jj)
            hreg[jj] = hrow[(size_t)(jb * 64 + jj) * DD + lane];

        #pragma unroll
        for (int jj = 0; jj < 64; ++jj) {
            #pragma unroll
            for (int ii = 0; ii < 16; ++ii) {
                const float pb = __shfl(p[ii], jj);
                O[ii] += pb * hreg[jj];
            }
        }
    }

    __shared__ float osh[NH][16][64];
    #pragma unroll
    for (int ii = 0; ii < 16; ++ii) {
        float Ls = L[ii];
        #pragma unroll
        for (int off = 1; off < 64; off <<= 1) Ls += __shfl_xor(Ls, off);
        osh[hd][ii][lane] = O[ii] * (0.25f / Ls);
    }
    __syncthreads();

    {
        const int i  = tid >> 4;
        const int d4 = (tid & 15) * 4;
        float4 s = {0.f, 0.f, 0.f, 0.f};
        #pragma unroll
        for (int h = 0; h < NH; ++h) {
            const float4 v = *(const float4*)&osh[h][i][d4];
            s.x += v.x; s.y += v.y; s.z += v.z; s.w += v.w;
        }
        *(float4*)(out + ((size_t)(b * NN) + i0 + i) * DD + d4) = s;
    }
}

extern "C" void kernel_launch(void* const* d_in, const int* in_sizes, int n_in,
                              void* d_out, int out_size, void* d_ws, size_t ws_size,
                              hipStream_t stream) {
    // Size-keyed assignment (all element counts distinct) to be robust to order.
    const float* x = nullptr; const int* adj = nullptr;
    const float* W = nullptr; const float* a = nullptr;
    for (int i = 0; i < n_in; ++i) {
        switch (in_sizes[i]) {
            case NB * NN * FIN:  x   = (const float*)d_in[i]; break;   // 1048576
            case NB * NN * NN:   adj = (const int*)d_in[i];   break;   // 16777216
            case FIN * 256:      W   = (const float*)d_in[i]; break;   // 32768
            case 2 * DD:         a   = (const float*)d_in[i]; break;   // 128
            default: break;
        }
    }
    if (!x)   x   = (const float*)d_in[0];
    if (!adj) adj = (const int*)d_in[1];
    if (!W)   W   = (const float*)d_in[2];
    if (!a)   a   = (const float*)d_in[3];
    float* out = (float*)d_out;

    char* ws = (char*)d_ws;
    float* h_ws  = (float*)(ws);
    float* ei_ws = (float*)(ws + 8388608);
    float* ej_ws = (float*)(ws + 8519680);

    k_hproj<<<dim3(NB * NN), dim3(256), 0, stream>>>(x, W, a, h_ws, ei_ws, ej_ws);
    k_attn_valu<<<dim3(128, NB), dim3(256), 0, stream>>>(adj, h_ws, ei_ws, ej_ws, out);
}

// Round 4
// 225.484 us; speedup vs baseline: 4.2492x; 4.2492x over previous
//
#include <hip/hip_runtime.h>

#define NN 2048
#define NH 4
#define DD 64
#define FIN 128
#define NB 4
#define ALPHA 0.2f

typedef unsigned short u16;
typedef short sh8 __attribute__((ext_vector_type(8)));
typedef float f32x4 __attribute__((ext_vector_type(4)));

static __device__ __forceinline__ u16 f2bf(float f) {
    unsigned int u = __builtin_bit_cast(unsigned int, f);
    u += 0x7fffu + ((u >> 16) & 1u);   // RNE
    return (u16)(u >> 16);
}

// ws layout (bytes):
//   h_ws [B][H][N][D] f32 @ 0        : 8388608
//   ei   [B][H][N]    f32 @ 8388608  : 131072
//   ej   [B][H][N]    f32 @ 8519680  : 131072
//   hT   [B][256][N] bf16 @ 8650752  : 4194304

__global__ __launch_bounds__(256)
void k_hproj(const float* __restrict__ x, const float* __restrict__ W,
             const float* __restrict__ a,
             float* __restrict__ h_ws, float* __restrict__ ei_ws, float* __restrict__ ej_ws) {
    const int ng   = blockIdx.x;
    const int b    = ng >> 11;
    const int n    = ng & 2047;
    const int c    = threadIdx.x;
    const int head = c >> 6;
    const int d    = c & 63;
    const int lane = threadIdx.x & 63;

    const float* xr = x + (size_t)ng * FIN;
    float acc = 0.f;
    #pragma unroll
    for (int kc = 0; kc < 32; ++kc) {
        const float4 xv = *(const float4*)(xr + kc * 4);
        acc += xv.x * W[(kc * 4 + 0) * 256 + c];
        acc += xv.y * W[(kc * 4 + 1) * 256 + c];
        acc += xv.z * W[(kc * 4 + 2) * 256 + c];
        acc += xv.w * W[(kc * 4 + 3) * 256 + c];
    }
    h_ws[((size_t)(b * NH + head) * NN + n) * DD + d] = acc;

    float eip = acc * a[d];
    float ejp = acc * a[64 + d];
    #pragma unroll
    for (int off = 1; off < 64; off <<= 1) {
        eip += __shfl_xor(eip, off);
        ejp += __shfl_xor(ejp, off);
    }
    if (lane == 0) {
        ei_ws[(size_t)(b * NH + head) * NN + n] = eip;
        ej_ws[(size_t)(b * NH + head) * NN + n] = ejp;
    }
}

// Transpose h_ws[bh][n][d] f32 -> hT[b][h*64+d][n] bf16. grid (32, 16), block 256.
__global__ __launch_bounds__(256)
void k_mkht(const float* __restrict__ h_ws, u16* __restrict__ hT) {
    const int nt  = blockIdx.x;      // n-tile 0..31
    const int bh  = blockIdx.y;      // 0..15
    const int tid = threadIdx.x;
    const int r0  = tid >> 6;        // 0..3
    const int d   = tid & 63;

    __shared__ float t[64][65];
    const float* src = h_ws + ((size_t)bh * NN + nt * 64) * DD;
    #pragma unroll
    for (int r = r0; r < 64; r += 4)
        t[r][d] = src[(size_t)r * DD + d];
    __syncthreads();

    u16* dst = hT + ((size_t)bh * DD) * NN + nt * 64;   // row (bh*64 + dr), col n
    const int n = tid & 63;
    #pragma unroll
    for (int dr = r0; dr < 64; dr += 4)
        dst[(size_t)dr * NN + n] = f2bf(t[n][dr]);
}

struct StageB { int4 a0, a1; float4 e0, e1; sh8 h0, h1, h2, h3; };

// grid (ib=128, b=4), block 256 (wave = head). Rows i in [ib*16,+16).
// Single-pass unnormalized softmax; P in MFMA A-layout; C/D layout discovered by runtime probe.
__global__ __launch_bounds__(256)
void k_attn(const int* __restrict__ adj, const u16* __restrict__ hT,
            const float* __restrict__ ei_g, const float* __restrict__ ej_g,
            float* __restrict__ out) {
    const int ib   = blockIdx.x;
    const int b    = blockIdx.y;
    const int tid  = threadIdx.x;
    const int hd   = tid >> 6;
    const int lane = tid & 63;
    const int ln15 = lane & 15;
    const int q    = lane >> 4;
    const int i0   = ib * 16;

    // ---- C/D layout probe (self-calibrating, ~free) ----
    sh8 pa, pb, qa, qb;
    #pragma unroll
    for (int ii = 0; ii < 8; ++ii) {
        pa[ii] = (short)f2bf((float)ln15);   // A[m][k] = m for all k
        pb[ii] = 0;
        qa[ii] = 0;
        qb[ii] = (short)f2bf((float)ln15);   // B[k][n] = n for all k
    }
    if (q == 0) { pb[0] = (short)f2bf(1.0f); qa[0] = (short)f2bf(1.0f); }
    f32x4 z = {};
    f32x4 prow = __builtin_amdgcn_mfma_f32_16x16x32_bf16(pa, pb, z, 0, 0, 0); // D[m][n]=m
    f32x4 pcol = __builtin_amdgcn_mfma_f32_16x16x32_bf16(qa, qb, z, 0, 0, 0); // D[m][n]=n
    int irow[4], icol[4];
    #pragma unroll
    for (int r = 0; r < 4; ++r) {
        irow[r] = (int)(prow[r] + 0.5f);
        icol[r] = (int)(pcol[r] + 0.5f);
    }

    const float eiv = ei_g[(size_t)(b * NH + hd) * NN + i0 + ln15];
    const int*   aptr  = adj  + ((size_t)(b * NN + i0 + ln15)) * NN + q * 8;
    const float* ejptr = ej_g + (size_t)(b * NH + hd) * NN + q * 8;
    const u16*   hptr  = hT   + ((size_t)(b * 256 + hd * 64 + ln15)) * NN + q * 8;

    f32x4 acc[4] = {};
    float lsum = 0.f;

    auto load_stage = [&](int jc) -> StageB {
        StageB s;
        s.a0 = *(const int4*)(aptr + jc);
        s.a1 = *(const int4*)(aptr + jc + 4);
        s.e0 = *(const float4*)(ejptr + jc);
        s.e1 = *(const float4*)(ejptr + jc + 4);
        s.h0 = *(const sh8*)(hptr + jc);
        s.h1 = *(const sh8*)(hptr + 16 * NN + jc);
        s.h2 = *(const sh8*)(hptr + 32 * NN + jc);
        s.h3 = *(const sh8*)(hptr + 48 * NN + jc);
        return s;
    };

    StageB s = load_stage(0);
    for (int jt = 0; jt < 64; ++jt) {
        StageB sn = load_stage(((jt + 1) & 63) * 32);   // wraps; last discarded

        const int   ai[8] = { s.a0.x, s.a0.y, s.a0.z, s.a0.w, s.a1.x, s.a1.y, s.a1.z, s.a1.w };
        const float ef[8] = { s.e0.x, s.e0.y, s.e0.z, s.e0.w, s.e1.x, s.e1.y, s.e1.z, s.e1.w };
        sh8 av;
        #pragma unroll
        for (int ii = 0; ii < 8; ++ii) {
            float e = eiv + ef[ii];
            e = (e >= 0.f) ? e : (ALPHA * e);
            float p = (ai[ii] != 0) ? __expf(e) : 0.f;
            lsum += p;
            av[ii] = (short)f2bf(p);
        }
        acc[0] = __builtin_amdgcn_mfma_f32_16x16x32_bf16(av, s.h0, acc[0], 0, 0, 0);
        acc[1] = __builtin_amdgcn_mfma_f32_16x16x32_bf16(av, s.h1, acc[1], 0, 0, 0);
        acc[2] = __builtin_amdgcn_mfma_f32_16x16x32_bf16(av, s.h2, acc[2], 0, 0, 0);
        acc[3] = __builtin_amdgcn_mfma_f32_16x16x32_bf16(av, s.h3, acc[3], 0, 0, 0);
        s = sn;
    }

    lsum += __shfl_xor(lsum, 16);
    lsum += __shfl_xor(lsum, 32);

    __shared__ float o_s[NH][16][64];
    __shared__ float l_s[NH][16];
    if (lane < 16) l_s[hd][lane] = lsum;   // row index from A-layout (m = lane&15)
    #pragma unroll
    for (int dt = 0; dt < 4; ++dt)
        #pragma unroll
        for (int r = 0; r < 4; ++r)
            o_s[hd][irow[r]][dt * 16 + icol[r]] = acc[dt][r];   // probe-mapped scatter
    __syncthreads();

    {
        const int base = tid * 4;
        const int i = base >> 6;
        const int d = base & 63;
        float inv[NH];
        #pragma unroll
        for (int h = 0; h < NH; ++h) inv[h] = 0.25f / l_s[h][i];
        float o0 = 0, o1 = 0, o2 = 0, o3 = 0;
        #pragma unroll
        for (int h = 0; h < NH; ++h) {
            const float4 v = *(const float4*)&o_s[h][i][d];
            o0 += v.x * inv[h]; o1 += v.y * inv[h]; o2 += v.z * inv[h]; o3 += v.w * inv[h];
        }
        float4 ov = { o0, o1, o2, o3 };
        *(float4*)(out + ((size_t)(b * NN) + i0 + i) * DD + d) = ov;
    }
}

extern "C" void kernel_launch(void* const* d_in, const int* in_sizes, int n_in,
                              void* d_out, int out_size, void* d_ws, size_t ws_size,
                              hipStream_t stream) {
    const float* x = nullptr; const int* adj = nullptr;
    const float* W = nullptr; const float* a = nullptr;
    for (int i = 0; i < n_in; ++i) {
        switch (in_sizes[i]) {
            case NB * NN * FIN:  x   = (const float*)d_in[i]; break;
            case NB * NN * NN:   adj = (const int*)d_in[i];   break;
            case FIN * 256:      W   = (const float*)d_in[i]; break;
            case 2 * DD:         a   = (const float*)d_in[i]; break;
            default: break;
        }
    }
    if (!x)   x   = (const float*)d_in[0];
    if (!adj) adj = (const int*)d_in[1];
    if (!W)   W   = (const float*)d_in[2];
    if (!a)   a   = (const float*)d_in[3];
    float* out = (float*)d_out;

    char* ws = (char*)d_ws;
    float* h_ws  = (float*)(ws);
    float* ei_ws = (float*)(ws + 8388608);
    float* ej_ws = (float*)(ws + 8519680);
    u16*   hT    = (u16*)(ws + 8650752);

    k_hproj<<<dim3(NB * NN), dim3(256), 0, stream>>>(x, W, a, h_ws, ei_ws, ej_ws);
    k_mkht<<<dim3(32, NB * NH), dim3(256), 0, stream>>>(h_ws, hT);
    k_attn<<<dim3(128, NB), dim3(256), 0, stream>>>(adj, hT, ei_ws, ej_ws, out);
}

// Round 5
// 208.304 us; speedup vs baseline: 4.5996x; 1.0825x over previous
//
#include <hip/hip_runtime.h>

#define NN 2048
#define NH 4
#define DD 64
#define FIN 128
#define NB 4

typedef unsigned short u16;
typedef unsigned int u32;
typedef short sh8 __attribute__((ext_vector_type(8)));
typedef float f32x4 __attribute__((ext_vector_type(4)));

static __device__ __forceinline__ u16 f2bf(float f) {   // RNE
    u32 u = __builtin_bit_cast(u32, f);
    u += 0x7fffu + ((u >> 16) & 1u);
    return (u16)(u >> 16);
}
// pack two floats to bf16x2 (lo=a, hi=b), round-to-nearest via +0x8000 then take hi16 (v_perm)
static __device__ __forceinline__ u32 pk_bf(float a, float b) {
    u32 ua = __builtin_bit_cast(u32, a) + 0x8000u;
    u32 ub = __builtin_bit_cast(u32, b) + 0x8000u;
    return __builtin_amdgcn_perm(ub, ua, 0x07060302u);
}

// ---- runtime C/D layout probe (verified load-bearing in R4) ----
static __device__ __forceinline__ void cd_probe(int ln15, int q, int* irow, int* icol) {
    sh8 pa, pb, qa, qb;
    #pragma unroll
    for (int ii = 0; ii < 8; ++ii) {
        pa[ii] = (short)f2bf((float)ln15);   // A[m][k] = m
        pb[ii] = 0;
        qa[ii] = 0;
        qb[ii] = (short)f2bf((float)ln15);   // B[k][n] = n
    }
    if (q == 0) { pb[0] = (short)f2bf(1.0f); qa[0] = (short)f2bf(1.0f); }
    f32x4 z = {};
    f32x4 prow = __builtin_amdgcn_mfma_f32_16x16x32_bf16(pa, pb, z, 0, 0, 0); // D=m
    f32x4 pcol = __builtin_amdgcn_mfma_f32_16x16x32_bf16(qa, qb, z, 0, 0, 0); // D=n
    #pragma unroll
    for (int r = 0; r < 4; ++r) {
        irow[r] = (int)(prow[r] + 0.5f);
        icol[r] = (int)(pcol[r] + 0.5f);
    }
}

// ws layout (bytes):
//   x_bf [B][N][FIN] bf16 @ 0         : 2097152
//   WT   [256][128]  bf16 @ 2097152   : 65536
//   ei   [B][H][N]   f32  @ 2162688   : 131072
//   ej   [B][H][N]   f32  @ 2293760   : 131072
//   hT   [B][256][N] bf16 @ 2424832   : 4194304
//   l_p  [B][128][js][H][16]      f32 @ 6619136 : 131072*js (alloc for js=4)
//   o_p  [B][128][js][H][16][64]  f32 @ 7143424 : 8388608*js

__global__ __launch_bounds__(256)
void k_prep(const float* __restrict__ x, const float* __restrict__ W,
            u16* __restrict__ x_bf, u16* __restrict__ WT) {
    const int bi = blockIdx.x;
    const int tid = threadIdx.x;
    if (bi < 1024) {
        const size_t idx = (size_t)bi * 1024 + tid * 4;
        const float4 v = *(const float4*)(x + idx);
        ushort4 o;
        o.x = f2bf(v.x); o.y = f2bf(v.y); o.z = f2bf(v.z); o.w = f2bf(v.w);
        *(ushort4*)(x_bf + idx) = o;
    } else {
        const int k = bi - 1024;            // 0..127
        WT[tid * FIN + k] = f2bf(W[k * 256 + tid]);
    }
}

// hT[b][c][n] = bf16( (x@W)[b][n][c] ), plus ei/ej. grid (32,4,4), block 256.
__global__ __launch_bounds__(256)
void k_gemm_h(const u16* __restrict__ x_bf, const u16* __restrict__ WT,
              const float* __restrict__ a,
              u16* __restrict__ hT, float* __restrict__ ei_g, float* __restrict__ ej_g) {
    const int nb = blockIdx.x, head = blockIdx.y, b = blockIdx.z;
    const int tid = threadIdx.x, w = tid >> 6, lane = tid & 63, ln15 = lane & 15, q = lane >> 4;
    const int c0 = head * 64 + w * 16, n0 = nb * 64;

    int irow[4], icol[4];
    cd_probe(ln15, q, irow, icol);

    f32x4 acc[4] = {};
    #pragma unroll
    for (int ks = 0; ks < 4; ++ks) {
        sh8 af = *(const sh8*)(WT + (size_t)(c0 + ln15) * FIN + ks * 32 + q * 8);
        #pragma unroll
        for (int nt = 0; nt < 4; ++nt) {
            sh8 bf = *(const sh8*)(x_bf + ((size_t)(b * NN + n0 + nt * 16 + ln15)) * FIN + ks * 32 + q * 8);
            acc[nt] = __builtin_amdgcn_mfma_f32_16x16x32_bf16(af, bf, acc[nt], 0, 0, 0);
        }
    }

    // canonicalize C/D through LDS using the probe mapping
    __shared__ float cs[4][4][16][16];
    #pragma unroll
    for (int nt = 0; nt < 4; ++nt)
        #pragma unroll
        for (int r = 0; r < 4; ++r)
            cs[w][nt][irow[r]][icol[r]] = acc[nt][r];
    __syncthreads();

    const int d0 = w * 16 + 4 * q;          // d = c & 63
    float a1v[4], a2v[4];
    #pragma unroll
    for (int r = 0; r < 4; ++r) { a1v[r] = a[d0 + r]; a2v[r] = a[64 + d0 + r]; }

    float eip[4], ejp[4];
    #pragma unroll
    for (int nt = 0; nt < 4; ++nt) {
        float se = 0.f, sj = 0.f;
        #pragma unroll
        for (int r = 0; r < 4; ++r) {
            const float v = cs[w][nt][4 * q + r][ln15];
            hT[((size_t)(b * 256 + c0 + 4 * q + r)) * NN + n0 + nt * 16 + ln15] = f2bf(v);
            se += v * a1v[r];
            sj += v * a2v[r];
        }
        eip[nt] = se; ejp[nt] = sj;
    }
    #pragma unroll
    for (int nt = 0; nt < 4; ++nt) {
        eip[nt] += __shfl_xor(eip[nt], 16);
        eip[nt] += __shfl_xor(eip[nt], 32);
        ejp[nt] += __shfl_xor(ejp[nt], 16);
        ejp[nt] += __shfl_xor(ejp[nt], 32);
    }
    __shared__ float eis[4][64], ejs[4][64];
    if (lane < 16) {
        #pragma unroll
        for (int nt = 0; nt < 4; ++nt) {
            eis[w][nt * 16 + lane] = eip[nt];
            ejs[w][nt * 16 + lane] = ejp[nt];
        }
    }
    __syncthreads();
    if (tid < 64) {
        const float se = eis[0][tid] + eis[1][tid] + eis[2][tid] + eis[3][tid];
        const float sj = ejs[0][tid] + ejs[1][tid] + ejs[2][tid] + ejs[3][tid];
        ei_g[(size_t)(b * NH + head) * NN + n0 + tid] = se;
        ej_g[(size_t)(b * NH + head) * NN + n0 + tid] = sj;
    }
}

struct StageB { int4 a0, a1; float4 e0, e1; sh8 h0, h1, h2, h3; };

// grid (ib=128, js, b=4), block 256 (wave = head). Writes unnormalized partials.
__global__ __launch_bounds__(256)
void k_attn(const int* __restrict__ adj, const u16* __restrict__ hT,
            const float* __restrict__ ei_g, const float* __restrict__ ej_g,
            float* __restrict__ o_part, float* __restrict__ l_part, int nj) {
    const int ib = blockIdx.x, js = blockIdx.y, b = blockIdx.z;
    const int js_n = gridDim.y;
    const int tid = threadIdx.x, hd = tid >> 6, lane = tid & 63, ln15 = lane & 15, q = lane >> 4;
    const int i0 = ib * 16;

    int irow[4], icol[4];
    cd_probe(ln15, q, irow, icol);

    const float eiv = ei_g[(size_t)(b * NH + hd) * NN + i0 + ln15];
    const int*   aptr  = adj  + ((size_t)(b * NN + i0 + ln15)) * NN + q * 8;
    const float* ejptr = ej_g + (size_t)(b * NH + hd) * NN + q * 8;
    const u16*   hptr  = hT   + ((size_t)(b * 256 + hd * 64 + ln15)) * NN + q * 8;

    f32x4 acc[4] = {};
    float lsum = 0.f;

    auto load_stage = [&](int jc) -> StageB {
        StageB s;
        s.a0 = *(const int4*)(aptr + jc);
        s.a1 = *(const int4*)(aptr + jc + 4);
        s.e0 = *(const float4*)(ejptr + jc);
        s.e1 = *(const float4*)(ejptr + jc + 4);
        s.h0 = *(const sh8*)(hptr + jc);
        s.h1 = *(const sh8*)(hptr + 16 * NN + jc);
        s.h2 = *(const sh8*)(hptr + 32 * NN + jc);
        s.h3 = *(const sh8*)(hptr + 48 * NN + jc);
        return s;
    };

    const int jt0 = js * nj;
    StageB s = load_stage(jt0 * 32);
    for (int t = 0; t < nj; ++t) {
        const int nxt = (t + 1 < nj) ? (jt0 + t + 1) * 32 : jt0 * 32;  // last discarded
        StageB sn = load_stage(nxt);

        const int   ai[8] = { s.a0.x, s.a0.y, s.a0.z, s.a0.w, s.a1.x, s.a1.y, s.a1.z, s.a1.w };
        const float ef[8] = { s.e0.x, s.e0.y, s.e0.z, s.e0.w, s.e1.x, s.e1.y, s.e1.z, s.e1.w };
        float p[8];
        #pragma unroll
        for (int ii = 0; ii < 8; ++ii) {
            float e = eiv + ef[ii];
            e = fmaxf(e, 0.2f * e);                 // LeakyReLU
            const float ex = __expf(e);
            p[ii] = (ai[ii] != 0) ? ex : 0.f;
            lsum += p[ii];
        }
        union { uint4 u; sh8 v; } av;
        av.u.x = pk_bf(p[0], p[1]);
        av.u.y = pk_bf(p[2], p[3]);
        av.u.z = pk_bf(p[4], p[5]);
        av.u.w = pk_bf(p[6], p[7]);

        acc[0] = __builtin_amdgcn_mfma_f32_16x16x32_bf16(av.v, s.h0, acc[0], 0, 0, 0);
        acc[1] = __builtin_amdgcn_mfma_f32_16x16x32_bf16(av.v, s.h1, acc[1], 0, 0, 0);
        acc[2] = __builtin_amdgcn_mfma_f32_16x16x32_bf16(av.v, s.h2, acc[2], 0, 0, 0);
        acc[3] = __builtin_amdgcn_mfma_f32_16x16x32_bf16(av.v, s.h3, acc[3], 0, 0, 0);
        s = sn;
    }

    lsum += __shfl_xor(lsum, 16);
    lsum += __shfl_xor(lsum, 32);

    const size_t pbase = (((size_t)b * 128 + ib) * js_n + js) * NH + hd;
    if (lane < 16) l_part[pbase * 16 + lane] = lsum;
    float* op = o_part + pbase * 1024;
    #pragma unroll
    for (int dt = 0; dt < 4; ++dt)
        #pragma unroll
        for (int r = 0; r < 4; ++r)
            op[(size_t)irow[r] * 64 + dt * 16 + icol[r]] = acc[dt][r];
}

// grid (128, 4), block 256. Sums js partials, normalizes, means over heads.
__global__ __launch_bounds__(256)
void k_combine(const float* __restrict__ o_part, const float* __restrict__ l_part,
               float* __restrict__ out, int js_n) {
    const int ib = blockIdx.x, b = blockIdx.y;
    const int tid = threadIdx.x;
    const int i = tid >> 4, d4 = (tid & 15) * 4;
    float4 sacc = {0.f, 0.f, 0.f, 0.f};
    #pragma unroll
    for (int h = 0; h < NH; ++h) {
        float l = 0.f;
        float4 oh = {0.f, 0.f, 0.f, 0.f};
        for (int js = 0; js < js_n; ++js) {
            const size_t pbase = (((size_t)b * 128 + ib) * js_n + js) * NH + h;
            l += l_part[pbase * 16 + i];
            const float4 v = *(const float4*)(o_part + pbase * 1024 + (size_t)i * 64 + d4);
            oh.x += v.x; oh.y += v.y; oh.z += v.z; oh.w += v.w;
        }
        const float inv = 0.25f / l;
        sacc.x += oh.x * inv; sacc.y += oh.y * inv; sacc.z += oh.z * inv; sacc.w += oh.w * inv;
    }
    *(float4*)(out + ((size_t)(b * NN) + ib * 16 + i) * DD + d4) = sacc;
}

extern "C" void kernel_launch(void* const* d_in, const int* in_sizes, int n_in,
                              void* d_out, int out_size, void* d_ws, size_t ws_size,
                              hipStream_t stream) {
    const float* x = nullptr; const int* adj = nullptr;
    const float* W = nullptr; const float* a = nullptr;
    for (int i = 0; i < n_in; ++i) {
        switch (in_sizes[i]) {
            case NB * NN * FIN:  x   = (const float*)d_in[i]; break;
            case NB * NN * NN:   adj = (const int*)d_in[i];   break;
            case FIN * 256:      W   = (const float*)d_in[i]; break;
            case 2 * DD:         a   = (const float*)d_in[i]; break;
            default: break;
        }
    }
    if (!x)   x   = (const float*)d_in[0];
    if (!adj) adj = (const int*)d_in[1];
    if (!W)   W   = (const float*)d_in[2];
    if (!a)   a   = (const float*)d_in[3];
    float* out = (float*)d_out;

    char* ws = (char*)d_ws;
    u16*   x_bf = (u16*)(ws);
    u16*   WT   = (u16*)(ws + 2097152);
    float* ei   = (float*)(ws + 2162688);
    float* ej   = (float*)(ws + 2293760);
    u16*   hT   = (u16*)(ws + 2424832);
    float* l_p  = (float*)(ws + 6619136);
    float* o_p  = (float*)(ws + 7143424);

    const size_t need4 = 7143424 + (size_t)4 * 8388608;
    const size_t need2 = 7143424 + (size_t)2 * 8388608;
    const int js_n = (ws_size >= need4) ? 4 : (ws_size >= need2) ? 2 : 1;

    k_prep<<<dim3(1152), dim3(256), 0, stream>>>(x, W, x_bf, WT);
    k_gemm_h<<<dim3(32, NH, NB), dim3(256), 0, stream>>>(x_bf, WT, a, hT, ei, ej);
    k_attn<<<dim3(128, js_n, NB), dim3(256), 0, stream>>>(adj, hT, ei, ej, o_p, l_p, 64 / js_n);
    k_combine<<<dim3(128, NB), dim3(256), 0, stream>>>(o_p, l_p, out, js_n);
}

// Round 6
// 195.096 us; speedup vs baseline: 4.9110x; 1.0677x over previous
//
#include <hip/hip_runtime.h>

#define NN 2048
#define NH 4
#define DD 64
#define FIN 128
#define NB 4

typedef unsigned short u16;
typedef unsigned int u32;
typedef short sh8 __attribute__((ext_vector_type(8)));
typedef float f32x4 __attribute__((ext_vector_type(4)));

static __device__ __forceinline__ u16 f2bf(float f) {   // RNE
    u32 u = __builtin_bit_cast(u32, f);
    u += 0x7fffu + ((u >> 16) & 1u);
    return (u16)(u >> 16);
}
static __device__ __forceinline__ u32 pk_bf(float a, float b) {
    u32 ua = __builtin_bit_cast(u32, a) + 0x8000u;
    u32 ub = __builtin_bit_cast(u32, b) + 0x8000u;
    return __builtin_amdgcn_perm(ub, ua, 0x07060302u);
}

// ---- runtime C/D layout probe (load-bearing since R4) ----
static __device__ __forceinline__ void cd_probe(int ln15, int q, int* irow, int* icol) {
    sh8 pa, pb, qa, qb;
    #pragma unroll
    for (int ii = 0; ii < 8; ++ii) {
        pa[ii] = (short)f2bf((float)ln15);   // A[m][k] = m
        pb[ii] = 0;
        qa[ii] = 0;
        qb[ii] = (short)f2bf((float)ln15);   // B[k][n] = n
    }
    if (q == 0) { pb[0] = (short)f2bf(1.0f); qa[0] = (short)f2bf(1.0f); }
    f32x4 z = {};
    f32x4 prow = __builtin_amdgcn_mfma_f32_16x16x32_bf16(pa, pb, z, 0, 0, 0);
    f32x4 pcol = __builtin_amdgcn_mfma_f32_16x16x32_bf16(qa, qb, z, 0, 0, 0);
    #pragma unroll
    for (int r = 0; r < 4; ++r) {
        irow[r] = (int)(prow[r] + 0.5f);
        icol[r] = (int)(pcol[r] + 0.5f);
    }
}

// ws layout (bytes):
//   x_bf [B][N][FIN] bf16 @ 0        : 2097152
//   WT   [256][128]  bf16 @ 2097152  : 65536
//   ei   [B][H][N]   f32  @ 2162688  : 131072
//   ej   [B][H][N]   f32  @ 2293760  : 131072
//   hT   [B][256][N] bf16 @ 2424832  : 4194304
//   msk  [B][64][N]  u32  @ 6619136  : 2097152   (bit k of msk[b][j32][i] = adj[b][i][j32*32+k])
//   l_p  @ 8716288 : 131072*js
//   o_p  @ 9240576 : 8388608*js

__global__ __launch_bounds__(256)
void k_prep(const float* __restrict__ x, const float* __restrict__ W,
            u16* __restrict__ x_bf, u16* __restrict__ WT) {
    const int bi = blockIdx.x;
    const int tid = threadIdx.x;
    if (bi < 1024) {
        const size_t idx = (size_t)bi * 1024 + tid * 4;
        const float4 v = *(const float4*)(x + idx);
        ushort4 o;
        o.x = f2bf(v.x); o.y = f2bf(v.y); o.z = f2bf(v.z); o.w = f2bf(v.w);
        *(ushort4*)(x_bf + idx) = o;
    } else {
        const int k = bi - 1024;
        WT[tid * FIN + k] = f2bf(W[k * 256 + tid]);
    }
}

// adj -> bitmask. wave-task t: b=t>>16, i=(t>>5)&2047, jc64=t&31. 2048 blocks x 256.
__global__ __launch_bounds__(256)
void k_pack(const int* __restrict__ adj, u32* __restrict__ msk) {
    const int wid  = (blockIdx.x * 256 + threadIdx.x) >> 6;   // 0..8191
    const int lane = threadIdx.x & 63;
    #pragma unroll 2
    for (int t = wid; t < NB * NN * 32; t += 8192) {
        const int jc = t & 31;
        const int i  = (t >> 5) & (NN - 1);
        const int b  = t >> 16;
        const int a  = adj[((size_t)(b * NN + i)) * NN + jc * 64 + lane];
        const unsigned long long m = __ballot(a != 0);
        if (lane == 0) {
            msk[((size_t)(b * 64 + jc * 2 + 0)) * NN + i] = (u32)m;
            msk[((size_t)(b * 64 + jc * 2 + 1)) * NN + i] = (u32)(m >> 32);
        }
    }
}

// hT[b][c][n] = bf16((x@W)[b][n][c]), plus ei/ej. grid (32,4,4), block 256.
__global__ __launch_bounds__(256)
void k_gemm_h(const u16* __restrict__ x_bf, const u16* __restrict__ WT,
              const float* __restrict__ a,
              u16* __restrict__ hT, float* __restrict__ ei_g, float* __restrict__ ej_g) {
    const int nb = blockIdx.x, head = blockIdx.y, b = blockIdx.z;
    const int tid = threadIdx.x, w = tid >> 6, lane = tid & 63, ln15 = lane & 15, q = lane >> 4;
    const int c0 = head * 64 + w * 16, n0 = nb * 64;

    int irow[4], icol[4];
    cd_probe(ln15, q, irow, icol);

    // preload ALL fragments (one latency exposure), then MFMA chain
    sh8 af[4], bf[4][4];
    #pragma unroll
    for (int ks = 0; ks < 4; ++ks)
        af[ks] = *(const sh8*)(WT + (size_t)(c0 + ln15) * FIN + ks * 32 + q * 8);
    #pragma unroll
    for (int nt = 0; nt < 4; ++nt)
        #pragma unroll
        for (int ks = 0; ks < 4; ++ks)
            bf[nt][ks] = *(const sh8*)(x_bf + ((size_t)(b * NN + n0 + nt * 16 + ln15)) * FIN + ks * 32 + q * 8);

    f32x4 acc[4] = {};
    #pragma unroll
    for (int ks = 0; ks < 4; ++ks)
        #pragma unroll
        for (int nt = 0; nt < 4; ++nt)
            acc[nt] = __builtin_amdgcn_mfma_f32_16x16x32_bf16(af[ks], bf[nt][ks], acc[nt], 0, 0, 0);

    __shared__ float cs[4][4][16][16];
    #pragma unroll
    for (int nt = 0; nt < 4; ++nt)
        #pragma unroll
        for (int r = 0; r < 4; ++r)
            cs[w][nt][irow[r]][icol[r]] = acc[nt][r];
    __syncthreads();

    const int d0 = w * 16 + 4 * q;
    float a1v[4], a2v[4];
    #pragma unroll
    for (int r = 0; r < 4; ++r) { a1v[r] = a[d0 + r]; a2v[r] = a[64 + d0 + r]; }

    float eip[4], ejp[4];
    #pragma unroll
    for (int nt = 0; nt < 4; ++nt) {
        float se = 0.f, sj = 0.f;
        #pragma unroll
        for (int r = 0; r < 4; ++r) {
            const float v = cs[w][nt][4 * q + r][ln15];
            hT[((size_t)(b * 256 + c0 + 4 * q + r)) * NN + n0 + nt * 16 + ln15] = f2bf(v);
            se += v * a1v[r];
            sj += v * a2v[r];
        }
        eip[nt] = se; ejp[nt] = sj;
    }
    #pragma unroll
    for (int nt = 0; nt < 4; ++nt) {
        eip[nt] += __shfl_xor(eip[nt], 16);
        eip[nt] += __shfl_xor(eip[nt], 32);
        ejp[nt] += __shfl_xor(ejp[nt], 16);
        ejp[nt] += __shfl_xor(ejp[nt], 32);
    }
    __shared__ float eis[4][64], ejs[4][64];
    if (lane < 16) {
        #pragma unroll
        for (int nt = 0; nt < 4; ++nt) {
            eis[w][nt * 16 + lane] = eip[nt];
            ejs[w][nt * 16 + lane] = ejp[nt];
        }
    }
    __syncthreads();
    if (tid < 64) {
        const float se = eis[0][tid] + eis[1][tid] + eis[2][tid] + eis[3][tid];
        const float sj = ejs[0][tid] + ejs[1][tid] + ejs[2][tid] + ejs[3][tid];
        ei_g[(size_t)(b * NH + head) * NN + n0 + tid] = se;
        ej_g[(size_t)(b * NH + head) * NN + n0 + tid] = sj;
    }
}

struct StageB { u32 m; float4 e0, e1; sh8 h0, h1, h2, h3; };

// grid (ib=128, js, b=4), block 256 (wave = head). Unnormalized partials.
__global__ __launch_bounds__(256)
void k_attn(const u32* __restrict__ msk, const u16* __restrict__ hT,
            const float* __restrict__ ei_g, const float* __restrict__ ej_g,
            float* __restrict__ o_part, float* __restrict__ l_part, int nj) {
    const int ib = blockIdx.x, js = blockIdx.y, b = blockIdx.z;
    const int js_n = gridDim.y;
    const int tid = threadIdx.x, hd = tid >> 6, lane = tid & 63, ln15 = lane & 15, q = lane >> 4;
    const int i0 = ib * 16;
    const int q8 = q * 8;

    int irow[4], icol[4];
    cd_probe(ln15, q, irow, icol);

    const float eiv = ei_g[(size_t)(b * NH + hd) * NN + i0 + ln15];
    const u32*   mptr  = msk  + (size_t)(b * 64) * NN + i0 + ln15;      // + j32*NN
    const float* ejptr = ej_g + (size_t)(b * NH + hd) * NN + q8;
    const u16*   hptr  = hT   + ((size_t)(b * 256 + hd * 64 + ln15)) * NN + q8;

    f32x4 acc[4] = {};
    float lsum = 0.f;

    auto load_stage = [&](int j32) -> StageB {
        StageB s;
        const int jc = j32 * 32;
        s.m  = mptr[(size_t)j32 * NN];
        s.e0 = *(const float4*)(ejptr + jc);
        s.e1 = *(const float4*)(ejptr + jc + 4);
        s.h0 = *(const sh8*)(hptr + jc);
        s.h1 = *(const sh8*)(hptr + 16 * NN + jc);
        s.h2 = *(const sh8*)(hptr + 32 * NN + jc);
        s.h3 = *(const sh8*)(hptr + 48 * NN + jc);
        return s;
    };

    const int jt0 = js * nj;
    StageB s = load_stage(jt0);
    for (int t = 0; t < nj; ++t) {
        StageB sn = load_stage((t + 1 < nj) ? (jt0 + t + 1) : jt0);   // last discarded

        const float ef[8] = { s.e0.x, s.e0.y, s.e0.z, s.e0.w, s.e1.x, s.e1.y, s.e1.z, s.e1.w };
        const u32 mq = s.m >> q8;
        float p[8];
        #pragma unroll
        for (int ii = 0; ii < 8; ++ii) {
            float e = eiv + ef[ii];
            e = fmaxf(e, 0.2f * e);
            const float ex = __expf(e);
            p[ii] = (mq & (1u << ii)) ? ex : 0.f;
            lsum += p[ii];
        }
        union { uint4 u; sh8 v; } av;
        av.u.x = pk_bf(p[0], p[1]);
        av.u.y = pk_bf(p[2], p[3]);
        av.u.z = pk_bf(p[4], p[5]);
        av.u.w = pk_bf(p[6], p[7]);

        acc[0] = __builtin_amdgcn_mfma_f32_16x16x32_bf16(av.v, s.h0, acc[0], 0, 0, 0);
        acc[1] = __builtin_amdgcn_mfma_f32_16x16x32_bf16(av.v, s.h1, acc[1], 0, 0, 0);
        acc[2] = __builtin_amdgcn_mfma_f32_16x16x32_bf16(av.v, s.h2, acc[2], 0, 0, 0);
        acc[3] = __builtin_amdgcn_mfma_f32_16x16x32_bf16(av.v, s.h3, acc[3], 0, 0, 0);
        s = sn;
    }

    lsum += __shfl_xor(lsum, 16);
    lsum += __shfl_xor(lsum, 32);

    const size_t pbase = (((size_t)b * 128 + ib) * js_n + js) * NH + hd;
    if (lane < 16) l_part[pbase * 16 + lane] = lsum;
    float* op = o_part + pbase * 1024;
    #pragma unroll
    for (int dt = 0; dt < 4; ++dt)
        #pragma unroll
        for (int r = 0; r < 4; ++r)
            op[(size_t)irow[r] * 64 + dt * 16 + icol[r]] = acc[dt][r];
}

__global__ __launch_bounds__(256)
void k_combine(const float* __restrict__ o_part, const float* __restrict__ l_part,
               float* __restrict__ out, int js_n) {
    const int ib = blockIdx.x, b = blockIdx.y;
    const int tid = threadIdx.x;
    const int i = tid >> 4, d4 = (tid & 15) * 4;
    float4 sacc = {0.f, 0.f, 0.f, 0.f};
    #pragma unroll
    for (int h = 0; h < NH; ++h) {
        float l = 0.f;
        float4 oh = {0.f, 0.f, 0.f, 0.f};
        for (int js = 0; js < js_n; ++js) {
            const size_t pbase = (((size_t)b * 128 + ib) * js_n + js) * NH + h;
            l += l_part[pbase * 16 + i];
            const float4 v = *(const float4*)(o_part + pbase * 1024 + (size_t)i * 64 + d4);
            oh.x += v.x; oh.y += v.y; oh.z += v.z; oh.w += v.w;
        }
        const float inv = 0.25f / l;
        sacc.x += oh.x * inv; sacc.y += oh.y * inv; sacc.z += oh.z * inv; sacc.w += oh.w * inv;
    }
    *(float4*)(out + ((size_t)(b * NN) + ib * 16 + i) * DD + d4) = sacc;
}

extern "C" void kernel_launch(void* const* d_in, const int* in_sizes, int n_in,
                              void* d_out, int out_size, void* d_ws, size_t ws_size,
                              hipStream_t stream) {
    const float* x = nullptr; const int* adj = nullptr;
    const float* W = nullptr; const float* a = nullptr;
    for (int i = 0; i < n_in; ++i) {
        switch (in_sizes[i]) {
            case NB * NN * FIN:  x   = (const float*)d_in[i]; break;
            case NB * NN * NN:   adj = (const int*)d_in[i];   break;
            case FIN * 256:      W   = (const float*)d_in[i]; break;
            case 2 * DD:         a   = (const float*)d_in[i]; break;
            default: break;
        }
    }
    if (!x)   x   = (const float*)d_in[0];
    if (!adj) adj = (const int*)d_in[1];
    if (!W)   W   = (const float*)d_in[2];
    if (!a)   a   = (const float*)d_in[3];
    float* out = (float*)d_out;

    char* ws = (char*)d_ws;
    u16*   x_bf = (u16*)(ws);
    u16*   WT   = (u16*)(ws + 2097152);
    float* ei   = (float*)(ws + 2162688);
    float* ej   = (float*)(ws + 2293760);
    u16*   hT   = (u16*)(ws + 2424832);
    u32*   msk  = (u32*)(ws + 6619136);
    float* l_p  = (float*)(ws + 8716288);
    float* o_p  = (float*)(ws + 9240576);

    const size_t need4 = 9240576 + (size_t)4 * 8388608;
    const size_t need2 = 9240576 + (size_t)2 * 8388608;
    const int js_n = (ws_size >= need4) ? 4 : (ws_size >= need2) ? 2 : 1;

    k_prep<<<dim3(1152), dim3(256), 0, stream>>>(x, W, x_bf, WT);
    k_pack<<<dim3(2048), dim3(256), 0, stream>>>(adj, msk);
    k_gemm_h<<<dim3(32, NH, NB), dim3(256), 0, stream>>>(x_bf, WT, a, hT, ei, ej);
    k_attn<<<dim3(128, js_n, NB), dim3(256), 0, stream>>>(msk, hT, ei, ej, o_p, l_p, 64 / js_n);
    k_combine<<<dim3(128, NB), dim3(256), 0, stream>>>(o_p, l_p, out, js_n);
}

// Round 7
// 161.461 us; speedup vs baseline: 5.9341x; 1.2083x over previous
//
#include <hip/hip_runtime.h>

#define NN 2048
#define NH 4
#define DD 64
#define FIN 128
#define NB 4
#define LOG2E 1.44269504f

typedef unsigned short u16;
typedef unsigned int u32;
typedef short sh8 __attribute__((ext_vector_type(8)));
typedef float f32x4 __attribute__((ext_vector_type(4)));

static __device__ __forceinline__ u16 f2bf(float f) {   // RNE
    u32 u = __builtin_bit_cast(u32, f);
    u += 0x7fffu + ((u >> 16) & 1u);
    return (u16)(u >> 16);
}
static __device__ __forceinline__ u32 pk_bf(float a, float b) {
    u32 ua = __builtin_bit_cast(u32, a) + 0x8000u;
    u32 ub = __builtin_bit_cast(u32, b) + 0x8000u;
    return __builtin_amdgcn_perm(ub, ua, 0x07060302u);
}
static __device__ __forceinline__ float fast_exp2(float x) {
    float r;
    asm("v_exp_f32 %0, %1" : "=v"(r) : "v"(x));
    return r;
}

// ---- runtime C/D layout probe (load-bearing since R4) ----
static __device__ __forceinline__ void cd_probe(int ln15, int q, int* irow, int* icol) {
    sh8 pa, pb, qa, qb;
    #pragma unroll
    for (int ii = 0; ii < 8; ++ii) {
        pa[ii] = (short)f2bf((float)ln15);   // A[m][k] = m
        pb[ii] = 0;
        qa[ii] = 0;
        qb[ii] = (short)f2bf((float)ln15);   // B[k][n] = n
    }
    if (q == 0) { pb[0] = (short)f2bf(1.0f); qa[0] = (short)f2bf(1.0f); }
    f32x4 z = {};
    f32x4 prow = __builtin_amdgcn_mfma_f32_16x16x32_bf16(pa, pb, z, 0, 0, 0);
    f32x4 pcol = __builtin_amdgcn_mfma_f32_16x16x32_bf16(qa, qb, z, 0, 0, 0);
    #pragma unroll
    for (int r = 0; r < 4; ++r) {
        irow[r] = (int)(prow[r] + 0.5f);
        icol[r] = (int)(pcol[r] + 0.5f);
    }
}

// ws layout (bytes):
//   x_bf [B][N][FIN] bf16 @ 0        : 2097152
//   WT   [256][128]  bf16 @ 2097152  : 65536
//   ei   [B][H][N]   f32  @ 2162688  : 131072   (pre-scaled by log2e)
//   ej   [B][H][N]   f32  @ 2293760  : 131072   (pre-scaled by log2e)
//   hT   [B][256][N] bf16 @ 2424832  : 4194304
//   msk  [B][64][N]  u32  @ 6619136  : 2097152
//   l_p  @ 8716288 : 131072*js
//   o_p  @ 9240576 : 8388608*js

__global__ __launch_bounds__(256)
void k_prep(const float* __restrict__ x, const float* __restrict__ W,
            u16* __restrict__ x_bf, u16* __restrict__ WT) {
    const int bi = blockIdx.x;
    const int tid = threadIdx.x;
    if (bi < 1024) {
        const size_t idx = (size_t)bi * 1024 + tid * 4;
        const float4 v = *(const float4*)(x + idx);
        ushort4 o;
        o.x = f2bf(v.x); o.y = f2bf(v.y); o.z = f2bf(v.z); o.w = f2bf(v.w);
        *(ushort4*)(x_bf + idx) = o;
    } else {
        const int k = bi - 1024;
        WT[tid * FIN + k] = f2bf(W[k * 256 + tid]);
    }
}

// adj -> bitmask, 4-way unrolled independent loads. 2048 blocks x 256.
__global__ __launch_bounds__(256)
void k_pack(const int* __restrict__ adj, u32* __restrict__ msk) {
    const int wid  = (blockIdx.x * 256 + threadIdx.x) >> 6;   // 0..8191
    const int lane = threadIdx.x & 63;
    for (int t0 = wid; t0 < NB * NN * 32; t0 += 32768) {
        int av[4];
        #pragma unroll
        for (int k = 0; k < 4; ++k) {
            const int t  = t0 + k * 8192;
            const int jc = t & 31;
            const int i  = (t >> 5) & (NN - 1);
            const int b  = t >> 16;
            av[k] = adj[((size_t)(b * NN + i)) * NN + jc * 64 + lane];
        }
        #pragma unroll
        for (int k = 0; k < 4; ++k) {
            const int t  = t0 + k * 8192;
            const int jc = t & 31;
            const int i  = (t >> 5) & (NN - 1);
            const int b  = t >> 16;
            const unsigned long long m = __ballot(av[k] != 0);
            if (lane == 0) {
                msk[((size_t)(b * 64 + jc * 2 + 0)) * NN + i] = (u32)m;
                msk[((size_t)(b * 64 + jc * 2 + 1)) * NN + i] = (u32)(m >> 32);
            }
        }
    }
}

// hT[b][c][n] = bf16((x@W)[b][n][c]), plus ei/ej (pre-scaled by log2e). grid (32,4,4).
__global__ __launch_bounds__(256, 2)
void k_gemm_h(const u16* __restrict__ x_bf, const u16* __restrict__ WT,
              const float* __restrict__ a,
              u16* __restrict__ hT, float* __restrict__ ei_g, float* __restrict__ ej_g) {
    const int nb = blockIdx.x, head = blockIdx.y, b = blockIdx.z;
    const int tid = threadIdx.x, w = tid >> 6, lane = tid & 63, ln15 = lane & 15, q = lane >> 4;
    const int c0 = head * 64 + w * 16, n0 = nb * 64;

    int irow[4], icol[4];
    cd_probe(ln15, q, irow, icol);

    sh8 af[4], bf[4][4];
    #pragma unroll
    for (int ks = 0; ks < 4; ++ks)
        af[ks] = *(const sh8*)(WT + (size_t)(c0 + ln15) * FIN + ks * 32 + q * 8);
    #pragma unroll
    for (int nt = 0; nt < 4; ++nt)
        #pragma unroll
        for (int ks = 0; ks < 4; ++ks)
            bf[nt][ks] = *(const sh8*)(x_bf + ((size_t)(b * NN + n0 + nt * 16 + ln15)) * FIN + ks * 32 + q * 8);

    f32x4 acc[4] = {};
    #pragma unroll
    for (int ks = 0; ks < 4; ++ks)
        #pragma unroll
        for (int nt = 0; nt < 4; ++nt)
            acc[nt] = __builtin_amdgcn_mfma_f32_16x16x32_bf16(af[ks], bf[nt][ks], acc[nt], 0, 0, 0);

    __shared__ float cs[4][4][16][16];
    #pragma unroll
    for (int nt = 0; nt < 4; ++nt)
        #pragma unroll
        for (int r = 0; r < 4; ++r)
            cs[w][nt][irow[r]][icol[r]] = acc[nt][r];
    __syncthreads();

    const int d0 = w * 16 + 4 * q;
    float a1v[4], a2v[4];
    #pragma unroll
    for (int r = 0; r < 4; ++r) {
        a1v[r] = a[d0 + r] * LOG2E;
        a2v[r] = a[64 + d0 + r] * LOG2E;
    }

    float eip[4], ejp[4];
    #pragma unroll
    for (int nt = 0; nt < 4; ++nt) {
        float se = 0.f, sj = 0.f;
        #pragma unroll
        for (int r = 0; r < 4; ++r) {
            const float v = cs[w][nt][4 * q + r][ln15];
            hT[((size_t)(b * 256 + c0 + 4 * q + r)) * NN + n0 + nt * 16 + ln15] = f2bf(v);
            se += v * a1v[r];
            sj += v * a2v[r];
        }
        eip[nt] = se; ejp[nt] = sj;
    }
    #pragma unroll
    for (int nt = 0; nt < 4; ++nt) {
        eip[nt] += __shfl_xor(eip[nt], 16);
        eip[nt] += __shfl_xor(eip[nt], 32);
        ejp[nt] += __shfl_xor(ejp[nt], 16);
        ejp[nt] += __shfl_xor(ejp[nt], 32);
    }
    __shared__ float eis[4][64], ejs[4][64];
    if (lane < 16) {
        #pragma unroll
        for (int nt = 0; nt < 4; ++nt) {
            eis[w][nt * 16 + lane] = eip[nt];
            ejs[w][nt * 16 + lane] = ejp[nt];
        }
    }
    __syncthreads();
    if (tid < 64) {
        const float se = eis[0][tid] + eis[1][tid] + eis[2][tid] + eis[3][tid];
        const float sj = ejs[0][tid] + ejs[1][tid] + ejs[2][tid] + ejs[3][tid];
        ei_g[(size_t)(b * NH + head) * NN + n0 + tid] = se;
        ej_g[(size_t)(b * NH + head) * NN + n0 + tid] = sj;
    }
}

// grid (ib=64, js, b=4), block 256 (wave = head). Two 16-row i-tiles per block.
__global__ __launch_bounds__(256, 4)
void k_attn(const u32* __restrict__ msk, const u16* __restrict__ hT,
            const float* __restrict__ ei_g, const float* __restrict__ ej_g,
            float* __restrict__ o_part, float* __restrict__ l_part, int nj) {
    const int ib = blockIdx.x, js = blockIdx.y, b = blockIdx.z;
    const int js_n = gridDim.y;
    const int tid = threadIdx.x, hd = tid >> 6, lane = tid & 63, ln15 = lane & 15, q = lane >> 4;
    const int q8 = q * 8;
    const int iA = ib * 32 + ln15;           // tile A row; tile B = +16

    int irow[4], icol[4];
    cd_probe(ln15, q, irow, icol);

    const size_t bhd = (size_t)(b * NH + hd) * NN;
    const float eivA = ei_g[bhd + iA];
    const float eivB = ei_g[bhd + iA + 16];
    const u32*   mptr = msk + (size_t)(b * 64) * NN;   // + j32*NN + i
    const float* ejp  = ej_g + bhd + q8;
    const u16*   hptr = hT + ((size_t)(b * 256 + hd * 64 + ln15)) * NN + q8;

    sh8 ones;
    #pragma unroll
    for (int ii = 0; ii < 8; ++ii) ones[ii] = (short)0x3F80;   // bf16 1.0

    f32x4 acc[8] = {};
    f32x4 accl[2] = {};

    const int jt0 = js * nj;
    u32 mA = mptr[(size_t)jt0 * NN + iA];
    u32 mB = mptr[(size_t)jt0 * NN + iA + 16];
    float4 e0 = *(const float4*)(ejp + jt0 * 32);
    float4 e1 = *(const float4*)(ejp + jt0 * 32 + 4);

    for (int t = 0; t < nj; ++t) {
        const int jc = (jt0 + t) * 32;
        const sh8 h0 = *(const sh8*)(hptr + jc);
        const sh8 h1 = *(const sh8*)(hptr + 16 * NN + jc);
        const sh8 h2 = *(const sh8*)(hptr + 32 * NN + jc);
        const sh8 h3 = *(const sh8*)(hptr + 48 * NN + jc);

        const float ef[8] = { e0.x, e0.y, e0.z, e0.w, e1.x, e1.y, e1.z, e1.w };
        const u32 mqA = mA >> q8;
        const u32 mqB = mB >> q8;

        // prefetch next stage's mask + ej
        const int tn = (t + 1 < nj) ? (jt0 + t + 1) : jt0;
        const u32 mAn = mptr[(size_t)tn * NN + iA];
        const u32 mBn = mptr[(size_t)tn * NN + iA + 16];
        const float4 e0n = *(const float4*)(ejp + tn * 32);
        const float4 e1n = *(const float4*)(ejp + tn * 32 + 4);

        float pA[8], pB[8];
        #pragma unroll
        for (int ii = 0; ii < 8; ++ii) {
            float eA = eivA + ef[ii];
            float eB = eivB + ef[ii];
            eA = fmaxf(eA, 0.2f * eA);
            eB = fmaxf(eB, 0.2f * eB);
            const float xA = fast_exp2(eA);
            const float xB = fast_exp2(eB);
            pA[ii] = (mqA & (1u << ii)) ? xA : 0.f;
            pB[ii] = (mqB & (1u << ii)) ? xB : 0.f;
        }
        union { uint4 u; sh8 v; } avA, avB;
        avA.u.x = pk_bf(pA[0], pA[1]); avA.u.y = pk_bf(pA[2], pA[3]);
        avA.u.z = pk_bf(pA[4], pA[5]); avA.u.w = pk_bf(pA[6], pA[7]);
        avB.u.x = pk_bf(pB[0], pB[1]); avB.u.y = pk_bf(pB[2], pB[3]);
        avB.u.z = pk_bf(pB[4], pB[5]); avB.u.w = pk_bf(pB[6], pB[7]);

        acc[0] = __builtin_amdgcn_mfma_f32_16x16x32_bf16(avA.v, h0, acc[0], 0, 0, 0);
        acc[1] = __builtin_amdgcn_mfma_f32_16x16x32_bf16(avA.v, h1, acc[1], 0, 0, 0);
        acc[2] = __builtin_amdgcn_mfma_f32_16x16x32_bf16(avA.v, h2, acc[2], 0, 0, 0);
        acc[3] = __builtin_amdgcn_mfma_f32_16x16x32_bf16(avA.v, h3, acc[3], 0, 0, 0);
        accl[0] = __builtin_amdgcn_mfma_f32_16x16x32_bf16(avA.v, ones, accl[0], 0, 0, 0);
        acc[4] = __builtin_amdgcn_mfma_f32_16x16x32_bf16(avB.v, h0, acc[4], 0, 0, 0);
        acc[5] = __builtin_amdgcn_mfma_f32_16x16x32_bf16(avB.v, h1, acc[5], 0, 0, 0);
        acc[6] = __builtin_amdgcn_mfma_f32_16x16x32_bf16(avB.v, h2, acc[6], 0, 0, 0);
        acc[7] = __builtin_amdgcn_mfma_f32_16x16x32_bf16(avB.v, h3, acc[7], 0, 0, 0);
        accl[1] = __builtin_amdgcn_mfma_f32_16x16x32_bf16(avB.v, ones, accl[1], 0, 0, 0);

        mA = mAn; mB = mBn; e0 = e0n; e1 = e1n;
    }

    const size_t pbA = (((size_t)b * 128 + ib * 2 + 0) * js_n + js) * NH + hd;
    const size_t pbB = (((size_t)b * 128 + ib * 2 + 1) * js_n + js) * NH + hd;
    #pragma unroll
    for (int r = 0; r < 4; ++r) {
        l_part[pbA * 16 + irow[r]] = accl[0][r];   // 4x duplicate same value, benign
        l_part[pbB * 16 + irow[r]] = accl[1][r];
    }
    float* opA = o_part + pbA * 1024;
    float* opB = o_part + pbB * 1024;
    #pragma unroll
    for (int dt = 0; dt < 4; ++dt)
        #pragma unroll
        for (int r = 0; r < 4; ++r) {
            opA[(size_t)irow[r] * 64 + dt * 16 + icol[r]] = acc[dt][r];
            opB[(size_t)irow[r] * 64 + dt * 16 + icol[r]] = acc[4 + dt][r];
        }
}

__global__ __launch_bounds__(256)
void k_combine(const float* __restrict__ o_part, const float* __restrict__ l_part,
               float* __restrict__ out, int js_n) {
    const int ib = blockIdx.x, b = blockIdx.y;
    const int tid = threadIdx.x;
    const int i = tid >> 4, d4 = (tid & 15) * 4;
    float4 sacc = {0.f, 0.f, 0.f, 0.f};
    #pragma unroll
    for (int h = 0; h < NH; ++h) {
        float l = 0.f;
        float4 oh = {0.f, 0.f, 0.f, 0.f};
        for (int js = 0; js < js_n; ++js) {
            const size_t pbase = (((size_t)b * 128 + ib) * js_n + js) * NH + h;
            l += l_part[pbase * 16 + i];
            const float4 v = *(const float4*)(o_part + pbase * 1024 + (size_t)i * 64 + d4);
            oh.x += v.x; oh.y += v.y; oh.z += v.z; oh.w += v.w;
        }
        const float inv = 0.25f / l;
        sacc.x += oh.x * inv; sacc.y += oh.y * inv; sacc.z += oh.z * inv; sacc.w += oh.w * inv;
    }
    *(float4*)(out + ((size_t)(b * NN) + ib * 16 + i) * DD + d4) = sacc;
}

extern "C" void kernel_launch(void* const* d_in, const int* in_sizes, int n_in,
                              void* d_out, int out_size, void* d_ws, size_t ws_size,
                              hipStream_t stream) {
    const float* x = nullptr; const int* adj = nullptr;
    const float* W = nullptr; const float* a = nullptr;
    for (int i = 0; i < n_in; ++i) {
        switch (in_sizes[i]) {
            case NB * NN * FIN:  x   = (const float*)d_in[i]; break;
            case NB * NN * NN:   adj = (const int*)d_in[i];   break;
            case FIN * 256:      W   = (const float*)d_in[i]; break;
            case 2 * DD:         a   = (const float*)d_in[i]; break;
            default: break;
        }
    }
    if (!x)   x   = (const float*)d_in[0];
    if (!adj) adj = (const int*)d_in[1];
    if (!W)   W   = (const float*)d_in[2];
    if (!a)   a   = (const float*)d_in[3];
    float* out = (float*)d_out;

    char* ws = (char*)d_ws;
    u16*   x_bf = (u16*)(ws);
    u16*   WT   = (u16*)(ws + 2097152);
    float* ei   = (float*)(ws + 2162688);
    float* ej   = (float*)(ws + 2293760);
    u16*   hT   = (u16*)(ws + 2424832);
    u32*   msk  = (u32*)(ws + 6619136);
    float* l_p  = (float*)(ws + 8716288);
    float* o_p  = (float*)(ws + 9240576);

    const size_t need4 = 9240576 + (size_t)4 * 8388608;
    const size_t need2 = 9240576 + (size_t)2 * 8388608;
    const int js_n = (ws_size >= need4) ? 4 : (ws_size >= need2) ? 2 : 1;

    k_prep<<<dim3(1152), dim3(256), 0, stream>>>(x, W, x_bf, WT);
    k_pack<<<dim3(2048), dim3(256), 0, stream>>>(adj, msk);
    k_gemm_h<<<dim3(32, NH, NB), dim3(256), 0, stream>>>(x_bf, WT, a, hT, ei, ej);
    k_attn<<<dim3(64, js_n, NB), dim3(256), 0, stream>>>(msk, hT, ei, ej, o_p, l_p, 64 / js_n);
    k_combine<<<dim3(128, NB), dim3(256), 0, stream>>>(o_p, l_p, out, js_n);
}

// Round 8
// 156.096 us; speedup vs baseline: 6.1380x; 1.0344x over previous
//
#include <hip/hip_runtime.h>

#define NN 2048
#define NH 4
#define DD 64
#define FIN 128
#define NB 4
#define LOG2E 1.44269504f

typedef unsigned short u16;
typedef unsigned int u32;
typedef short sh8 __attribute__((ext_vector_type(8)));
typedef float f32x4 __attribute__((ext_vector_type(4)));

static __device__ __forceinline__ u16 f2bf(float f) {   // RNE
    u32 u = __builtin_bit_cast(u32, f);
    u += 0x7fffu + ((u >> 16) & 1u);
    return (u16)(u >> 16);
}
static __device__ __forceinline__ u32 pk_bf(float a, float b) {
    u32 ua = __builtin_bit_cast(u32, a) + 0x8000u;
    u32 ub = __builtin_bit_cast(u32, b) + 0x8000u;
    return __builtin_amdgcn_perm(ub, ua, 0x07060302u);
}
static __device__ __forceinline__ float fast_exp2(float x) {
    float r;
    asm("v_exp_f32 %0, %1" : "=v"(r) : "v"(x));
    return r;
}

// ---- runtime C/D layout probe (load-bearing since R4) ----
static __device__ __forceinline__ void cd_probe(int ln15, int q, int* irow, int* icol) {
    sh8 pa, pb, qa, qb;
    #pragma unroll
    for (int ii = 0; ii < 8; ++ii) {
        pa[ii] = (short)f2bf((float)ln15);   // A[m][k] = m
        pb[ii] = 0;
        qa[ii] = 0;
        qb[ii] = (short)f2bf((float)ln15);   // B[k][n] = n
    }
    if (q == 0) { pb[0] = (short)f2bf(1.0f); qa[0] = (short)f2bf(1.0f); }
    f32x4 z = {};
    f32x4 prow = __builtin_amdgcn_mfma_f32_16x16x32_bf16(pa, pb, z, 0, 0, 0);
    f32x4 pcol = __builtin_amdgcn_mfma_f32_16x16x32_bf16(qa, qb, z, 0, 0, 0);
    #pragma unroll
    for (int r = 0; r < 4; ++r) {
        irow[r] = (int)(prow[r] + 0.5f);
        icol[r] = (int)(pcol[r] + 0.5f);
    }
}

// ws layout (bytes):
//   WT   [256][128]  bf16 @ 0        : 65536
//   ei   [B][H][N]   f32  @ 65536    : 131072   (pre-scaled by log2e)
//   ej   [B][H][N]   f32  @ 196608   : 131072   (pre-scaled by log2e)
//   hT   [B][256][N] bf16 @ 327680   : 4194304
//   msk  [B][64][N]  u32  @ 4521984  : 2097152
//   l_p  @ 6619136 : 131072*js
//   o_p  @ 7143424 : 8388608*js

// blocks 0..2047: adj -> bitmask. blocks 2048..2079: W -> WT (bf16 transpose).
__global__ __launch_bounds__(256)
void k_pack(const int* __restrict__ adj, const float* __restrict__ W,
            u32* __restrict__ msk, u16* __restrict__ WT) {
    const int tid = threadIdx.x;
    if (blockIdx.x < 2048) {
        const int wid  = (blockIdx.x * 256 + tid) >> 6;   // 0..8191
        const int lane = tid & 63;
        for (int t0 = wid; t0 < NB * NN * 32; t0 += 32768) {
            int av[4];
            #pragma unroll
            for (int k = 0; k < 4; ++k) {
                const int t  = t0 + k * 8192;
                const int jc = t & 31;
                const int i  = (t >> 5) & (NN - 1);
                const int b  = t >> 16;
                av[k] = adj[((size_t)(b * NN + i)) * NN + jc * 64 + lane];
            }
            #pragma unroll
            for (int k = 0; k < 4; ++k) {
                const int t  = t0 + k * 8192;
                const int jc = t & 31;
                const int i  = (t >> 5) & (NN - 1);
                const int b  = t >> 16;
                const unsigned long long m = __ballot(av[k] != 0);
                if (lane == 0) {
                    msk[((size_t)(b * 64 + jc * 2 + 0)) * NN + i] = (u32)m;
                    msk[((size_t)(b * 64 + jc * 2 + 1)) * NN + i] = (u32)(m >> 32);
                }
            }
        }
    } else {
        const int bt  = blockIdx.x - 2048;   // 0..31
        const int kt  = bt & 3;              // k-tile (4 x 32 = 128)
        const int ct8 = bt >> 2;             // c-tile (8 x 32 = 256)
        __shared__ float tile[32][33];
        const int rr = tid >> 5, cc = tid & 31;
        #pragma unroll
        for (int i = 0; i < 4; ++i)
            tile[rr + 8 * i][cc] = W[(size_t)(kt * 32 + rr + 8 * i) * 256 + ct8 * 32 + cc];
        __syncthreads();
        #pragma unroll
        for (int i = 0; i < 4; ++i)
            WT[(size_t)(ct8 * 32 + rr + 8 * i) * FIN + kt * 32 + cc] = f2bf(tile[cc][rr + 8 * i]);
    }
}

// hT[b][c][n] = bf16((x@W)[b][n][c]) + ei/ej (log2e-scaled). grid (nb=32, b=4), wave = head.
__global__ __launch_bounds__(256)
void k_gemm_h(const float* __restrict__ x, const u16* __restrict__ WT,
              const float* __restrict__ a,
              u16* __restrict__ hT, float* __restrict__ ei_g, float* __restrict__ ej_g) {
    const int nb = blockIdx.x, b = blockIdx.y;
    const int tid = threadIdx.x, hd = tid >> 6, lane = tid & 63, ln15 = lane & 15, q = lane >> 4;
    const int q8 = q * 8;
    const int n0 = nb * 64;

    __shared__ u16 xs[64][136];          // +8 pad: kills 16-way bank conflict on b128 reads
    __shared__ float cs[4][4][4][16][16]; // [hd][ct][nt][row][col], fully private -> no barriers
    {
        const int col = (tid & 31) * 4;
        const int r0  = tid >> 5;
        #pragma unroll
        for (int rr = 0; rr < 8; ++rr) {
            const int row = r0 + rr * 8;
            const float4 v = *(const float4*)(x + ((size_t)(b * NN + n0 + row)) * FIN + col);
            *(u32*)&xs[row][col]     = pk_bf(v.x, v.y);
            *(u32*)&xs[row][col + 2] = pk_bf(v.z, v.w);
        }
    }
    __syncthreads();

    int irow[4], icol[4];
    cd_probe(ln15, q, irow, icol);

    f32x4 acc[4][4] = {};                // [ct][nt]
    #pragma unroll
    for (int ks = 0; ks < 4; ++ks) {
        sh8 af[4], bfr[4];
        #pragma unroll
        for (int ct = 0; ct < 4; ++ct)
            af[ct] = *(const sh8*)(WT + (size_t)(hd * 64 + ct * 16 + ln15) * FIN + ks * 32 + q8);
        #pragma unroll
        for (int nt = 0; nt < 4; ++nt)
            bfr[nt] = *(const sh8*)&xs[nt * 16 + ln15][ks * 32 + q8];
        #pragma unroll
        for (int ct = 0; ct < 4; ++ct)
            #pragma unroll
            for (int nt = 0; nt < 4; ++nt)
                acc[ct][nt] = __builtin_amdgcn_mfma_f32_16x16x32_bf16(af[ct], bfr[nt], acc[ct][nt], 0, 0, 0);
    }

    float a1v[4][4], a2v[4][4];
    #pragma unroll
    for (int ct = 0; ct < 4; ++ct)
        #pragma unroll
        for (int r = 0; r < 4; ++r) {
            const int d = ct * 16 + 4 * q + r;
            a1v[ct][r] = a[d] * LOG2E;
            a2v[ct][r] = a[64 + d] * LOG2E;
        }

    float eip[4] = {}, ejq[4] = {};
    #pragma unroll
    for (int ct = 0; ct < 4; ++ct) {
        #pragma unroll
        for (int nt = 0; nt < 4; ++nt)
            #pragma unroll
            for (int r = 0; r < 4; ++r)
                cs[hd][ct][nt][irow[r]][icol[r]] = acc[ct][nt][r];
        #pragma unroll
        for (int nt = 0; nt < 4; ++nt) {
            #pragma unroll
            for (int r = 0; r < 4; ++r) {
                const float v = cs[hd][ct][nt][4 * q + r][ln15];
                const int d = ct * 16 + 4 * q + r;
                hT[((size_t)(b * 256 + hd * 64 + d)) * NN + n0 + nt * 16 + ln15] = f2bf(v);
                eip[nt] += v * a1v[ct][r];
                ejq[nt] += v * a2v[ct][r];
            }
        }
    }
    #pragma unroll
    for (int nt = 0; nt < 4; ++nt) {
        eip[nt] += __shfl_xor(eip[nt], 16);
        eip[nt] += __shfl_xor(eip[nt], 32);
        ejq[nt] += __shfl_xor(ejq[nt], 16);
        ejq[nt] += __shfl_xor(ejq[nt], 32);
    }
    if (lane < 16) {
        const size_t bhd = (size_t)(b * NH + hd) * NN;
        #pragma unroll
        for (int nt = 0; nt < 4; ++nt) {
            ei_g[bhd + n0 + nt * 16 + lane] = eip[nt];
            ej_g[bhd + n0 + nt * 16 + lane] = ejq[nt];
        }
    }
}

// grid (ib=64, js, b=4), block 256 (wave = head). Fully software-pipelined.
__global__ __launch_bounds__(256, 3)
void k_attn(const u32* __restrict__ msk, const u16* __restrict__ hT,
            const float* __restrict__ ei_g, const float* __restrict__ ej_g,
            float* __restrict__ o_part, float* __restrict__ l_part, int nj) {
    const int ib = blockIdx.x, js = blockIdx.y, b = blockIdx.z;
    const int js_n = gridDim.y;
    const int tid = threadIdx.x, hd = tid >> 6, lane = tid & 63, ln15 = lane & 15, q = lane >> 4;
    const int q8 = q * 8;
    const int iA = ib * 32 + ln15;

    int irow[4], icol[4];
    cd_probe(ln15, q, irow, icol);

    const size_t bhd = (size_t)(b * NH + hd) * NN;
    const float eivA = ei_g[bhd + iA];
    const float eivB = ei_g[bhd + iA + 16];
    const u32*   mptr = msk + (size_t)(b * 64) * NN;
    const float* ejp  = ej_g + bhd + q8;
    const u16*   hptr = hT + ((size_t)(b * 256 + hd * 64 + ln15)) * NN + q8;

    sh8 ones;
    #pragma unroll
    for (int ii = 0; ii < 8; ++ii) ones[ii] = (short)0x3F80;

    f32x4 acc[8] = {};
    f32x4 accl[2] = {};

    const int jt0 = js * nj;
    // preload stage 0
    u32 mA = mptr[(size_t)jt0 * NN + iA];
    u32 mB = mptr[(size_t)jt0 * NN + iA + 16];
    float4 e0 = *(const float4*)(ejp + jt0 * 32);
    float4 e1 = *(const float4*)(ejp + jt0 * 32 + 4);
    sh8 h0 = *(const sh8*)(hptr + jt0 * 32);
    sh8 h1 = *(const sh8*)(hptr + 16 * NN + jt0 * 32);
    sh8 h2 = *(const sh8*)(hptr + 32 * NN + jt0 * 32);
    sh8 h3 = *(const sh8*)(hptr + 48 * NN + jt0 * 32);

    for (int t = 0; t < nj; ++t) {
        // issue ALL next-stage loads first (full iteration of latency cover)
        const int tn  = (t + 1 < nj) ? jt0 + t + 1 : jt0;
        const int jcn = tn * 32;
        const u32 mAn = mptr[(size_t)tn * NN + iA];
        const u32 mBn = mptr[(size_t)tn * NN + iA + 16];
        const float4 e0n = *(const float4*)(ejp + jcn);
        const float4 e1n = *(const float4*)(ejp + jcn + 4);
        const sh8 h0n = *(const sh8*)(hptr + jcn);
        const sh8 h1n = *(const sh8*)(hptr + 16 * NN + jcn);
        const sh8 h2n = *(const sh8*)(hptr + 32 * NN + jcn);
        const sh8 h3n = *(const sh8*)(hptr + 48 * NN + jcn);

        // compute current stage entirely from registers
        const float ef[8] = { e0.x, e0.y, e0.z, e0.w, e1.x, e1.y, e1.z, e1.w };
        const u32 mqA = mA >> q8;
        const u32 mqB = mB >> q8;
        float pA[8], pB[8];
        #pragma unroll
        for (int ii = 0; ii < 8; ++ii) {
            float eA = eivA + ef[ii];
            float eB = eivB + ef[ii];
            eA = fmaxf(eA, 0.2f * eA);
            eB = fmaxf(eB, 0.2f * eB);
            const float xA = fast_exp2(eA);
            const float xB = fast_exp2(eB);
            pA[ii] = (mqA & (1u << ii)) ? xA : 0.f;
            pB[ii] = (mqB & (1u << ii)) ? xB : 0.f;
        }
        union { uint4 u; sh8 v; } avA, avB;
        avA.u.x = pk_bf(pA[0], pA[1]); avA.u.y = pk_bf(pA[2], pA[3]);
        avA.u.z = pk_bf(pA[4], pA[5]); avA.u.w = pk_bf(pA[6], pA[7]);
        avB.u.x = pk_bf(pB[0], pB[1]); avB.u.y = pk_bf(pB[2], pB[3]);
        avB.u.z = pk_bf(pB[4], pB[5]); avB.u.w = pk_bf(pB[6], pB[7]);

        acc[0] = __builtin_amdgcn_mfma_f32_16x16x32_bf16(avA.v, h0, acc[0], 0, 0, 0);
        acc[1] = __builtin_amdgcn_mfma_f32_16x16x32_bf16(avA.v, h1, acc[1], 0, 0, 0);
        acc[2] = __builtin_amdgcn_mfma_f32_16x16x32_bf16(avA.v, h2, acc[2], 0, 0, 0);
        acc[3] = __builtin_amdgcn_mfma_f32_16x16x32_bf16(avA.v, h3, acc[3], 0, 0, 0);
        accl[0] = __builtin_amdgcn_mfma_f32_16x16x32_bf16(avA.v, ones, accl[0], 0, 0, 0);
        acc[4] = __builtin_amdgcn_mfma_f32_16x16x32_bf16(avB.v, h0, acc[4], 0, 0, 0);
        acc[5] = __builtin_amdgcn_mfma_f32_16x16x32_bf16(avB.v, h1, acc[5], 0, 0, 0);
        acc[6] = __builtin_amdgcn_mfma_f32_16x16x32_bf16(avB.v, h2, acc[6], 0, 0, 0);
        acc[7] = __builtin_amdgcn_mfma_f32_16x16x32_bf16(avB.v, h3, acc[7], 0, 0, 0);
        accl[1] = __builtin_amdgcn_mfma_f32_16x16x32_bf16(avB.v, ones, accl[1], 0, 0, 0);

        mA = mAn; mB = mBn; e0 = e0n; e1 = e1n;
        h0 = h0n; h1 = h1n; h2 = h2n; h3 = h3n;
    }

    const size_t pbA = (((size_t)b * 128 + ib * 2 + 0) * js_n + js) * NH + hd;
    const size_t pbB = (((size_t)b * 128 + ib * 2 + 1) * js_n + js) * NH + hd;
    #pragma unroll
    for (int r = 0; r < 4; ++r) {
        l_part[pbA * 16 + irow[r]] = accl[0][r];
        l_part[pbB * 16 + irow[r]] = accl[1][r];
    }
    float* opA = o_part + pbA * 1024;
    float* opB = o_part + pbB * 1024;
    #pragma unroll
    for (int dt = 0; dt < 4; ++dt)
        #pragma unroll
        for (int r = 0; r < 4; ++r) {
            opA[(size_t)irow[r] * 64 + dt * 16 + icol[r]] = acc[dt][r];
            opB[(size_t)irow[r] * 64 + dt * 16 + icol[r]] = acc[4 + dt][r];
        }
}

template <int JS>
__global__ __launch_bounds__(256)
void k_combine(const float* __restrict__ o_part, const float* __restrict__ l_part,
               float* __restrict__ out) {
    const int ib = blockIdx.x, b = blockIdx.y;
    const int tid = threadIdx.x;
    const int i = tid >> 4, d4 = (tid & 15) * 4;
    float  lv[NH][JS];
    float4 ov[NH][JS];
    #pragma unroll
    for (int h = 0; h < NH; ++h)
        #pragma unroll
        for (int js = 0; js < JS; ++js) {
            const size_t pbase = (((size_t)b * 128 + ib) * JS + js) * NH + h;
            lv[h][js] = l_part[pbase * 16 + i];
            ov[h][js] = *(const float4*)(o_part + pbase * 1024 + (size_t)i * 64 + d4);
        }
    float4 sacc = {0.f, 0.f, 0.f, 0.f};
    #pragma unroll
    for (int h = 0; h < NH; ++h) {
        float l = 0.f;
        float4 oh = {0.f, 0.f, 0.f, 0.f};
        #pragma unroll
        for (int js = 0; js < JS; ++js) {
            l += lv[h][js];
            oh.x += ov[h][js].x; oh.y += ov[h][js].y;
            oh.z += ov[h][js].z; oh.w += ov[h][js].w;
        }
        const float inv = 0.25f / l;
        sacc.x += oh.x * inv; sacc.y += oh.y * inv;
        sacc.z += oh.z * inv; sacc.w += oh.w * inv;
    }
    *(float4*)(out + ((size_t)(b * NN) + ib * 16 + i) * DD + d4) = sacc;
}

extern "C" void kernel_launch(void* const* d_in, const int* in_sizes, int n_in,
                              void* d_out, int out_size, void* d_ws, size_t ws_size,
                              hipStream_t stream) {
    const float* x = nullptr; const int* adj = nullptr;
    const float* W = nullptr; const float* a = nullptr;
    for (int i = 0; i < n_in; ++i) {
        switch (in_sizes[i]) {
            case NB * NN * FIN:  x   = (const float*)d_in[i]; break;
            case NB * NN * NN:   adj = (const int*)d_in[i];   break;
            case FIN * 256:      W   = (const float*)d_in[i]; break;
            case 2 * DD:         a   = (const float*)d_in[i]; break;
            default: break;
        }
    }
    if (!x)   x   = (const float*)d_in[0];
    if (!adj) adj = (const int*)d_in[1];
    if (!W)   W   = (const float*)d_in[2];
    if (!a)   a   = (const float*)d_in[3];
    float* out = (float*)d_out;

    char* ws = (char*)d_ws;
    u16*   WT  = (u16*)(ws);
    float* ei  = (float*)(ws + 65536);
    float* ej  = (float*)(ws + 196608);
    u16*   hT  = (u16*)(ws + 327680);
    u32*   msk = (u32*)(ws + 4521984);
    float* l_p = (float*)(ws + 6619136);
    float* o_p = (float*)(ws + 7143424);

    const size_t need4 = 7143424 + (size_t)4 * 8388608;
    const size_t need2 = 7143424 + (size_t)2 * 8388608;
    const int js_n = (ws_size >= need4) ? 4 : (ws_size >= need2) ? 2 : 1;

    k_pack<<<dim3(2080), dim3(256), 0, stream>>>(adj, W, msk, WT);
    k_gemm_h<<<dim3(32, NB), dim3(256), 0, stream>>>(x, WT, a, hT, ei, ej);
    k_attn<<<dim3(64, js_n, NB), dim3(256), 0, stream>>>(msk, hT, ei, ej, o_p, l_p, 64 / js_n);
    if (js_n == 4)      k_combine<4><<<dim3(128, NB), dim3(256), 0, stream>>>(o_p, l_p, out);
    else if (js_n == 2) k_combine<2><<<dim3(128, NB), dim3(256), 0, stream>>>(o_p, l_p, out);
    else                k_combine<1><<<dim3(128, NB), dim3(256), 0, stream>>>(o_p, l_p, out);
}

// Round 9
// 146.445 us; speedup vs baseline: 6.5425x; 1.0659x over previous
//
#include <hip/hip_runtime.h>

#define NN 2048
#define NH 4
#define DD 64
#define FIN 128
#define NB 4
#define LOG2E 1.44269504f

typedef unsigned short u16;
typedef unsigned int u32;
typedef short sh8 __attribute__((ext_vector_type(8)));
typedef float f32x4 __attribute__((ext_vector_type(4)));

static __device__ __forceinline__ u16 f2bf(float f) {   // RNE
    u32 u = __builtin_bit_cast(u32, f);
    u += 0x7fffu + ((u >> 16) & 1u);
    return (u16)(u >> 16);
}
static __device__ __forceinline__ u32 pk_bf(float a, float b) {
    u32 ua = __builtin_bit_cast(u32, a) + 0x8000u;
    u32 ub = __builtin_bit_cast(u32, b) + 0x8000u;
    return __builtin_amdgcn_perm(ub, ua, 0x07060302u);
}
static __device__ __forceinline__ float fast_exp2(float x) {
    float r;
    asm("v_exp_f32 %0, %1" : "=v"(r) : "v"(x));
    return r;
}

// ---- runtime C/D layout probe (load-bearing since R4) ----
static __device__ __forceinline__ void cd_probe(int ln15, int q, int* irow, int* icol) {
    sh8 pa, pb, qa, qb;
    #pragma unroll
    for (int ii = 0; ii < 8; ++ii) {
        pa[ii] = (short)f2bf((float)ln15);   // A[m][k] = m
        pb[ii] = 0;
        qa[ii] = 0;
        qb[ii] = (short)f2bf((float)ln15);   // B[k][n] = n
    }
    if (q == 0) { pb[0] = (short)f2bf(1.0f); qa[0] = (short)f2bf(1.0f); }
    f32x4 z = {};
    f32x4 prow = __builtin_amdgcn_mfma_f32_16x16x32_bf16(pa, pb, z, 0, 0, 0);
    f32x4 pcol = __builtin_amdgcn_mfma_f32_16x16x32_bf16(qa, qb, z, 0, 0, 0);
    #pragma unroll
    for (int r = 0; r < 4; ++r) {
        irow[r] = (int)(prow[r] + 0.5f);
        icol[r] = (int)(pcol[r] + 0.5f);
    }
}

// ws layout (bytes):
//   WT   [256][128] bf16 @ 0        : 65536
//   ei   [B][H][N]  f32  @ 65536    : 131072   (log2e-scaled)
//   ej   [B][H][N]  f32  @ 196608   : 131072   (log2e-scaled)
//   hTf  fragment-major  @ 327680   : 4194304  ([b][hd][jt64][dt4][lane64][8] bf16)
//   msk  [B][64][N] u32  @ 4521984  : 2097152
//   l_p  @ 6619136 : 131072*js
//   o_p  @ 7143424 : 8388608*js

// blocks 0..2047: adj -> bitmask (int4/lane, nibble + shfl-OR). 2048..2079: W -> WT.
__global__ __launch_bounds__(256)
void k_pack(const int* __restrict__ adj, const float* __restrict__ W,
            u32* __restrict__ msk, u16* __restrict__ WT) {
    const int tid = threadIdx.x;
    if (blockIdx.x < 2048) {
        const int wid  = (blockIdx.x * 256 + tid) >> 6;   // 0..8191
        const int lane = tid & 63;
        for (int t = wid; t < NB * NN * 8; t += 8192) {
            const int c256 = t & 7;
            const int i    = (t >> 3) & (NN - 1);
            const int b    = t >> 14;
            const int4 v = *(const int4*)(adj + ((size_t)(b * NN + i)) * NN + c256 * 256 + lane * 4);
            u32 nib = (v.x ? 1u : 0u) | (v.y ? 2u : 0u) | (v.z ? 4u : 0u) | (v.w ? 8u : 0u);
            u32 w = nib << (4 * (lane & 7));
            w |= __shfl_xor(w, 1);
            w |= __shfl_xor(w, 2);
            w |= __shfl_xor(w, 4);
            if ((lane & 7) == 0)
                msk[((size_t)(b * 64 + c256 * 8 + (lane >> 3))) * NN + i] = w;
        }
    } else {
        const int bt  = blockIdx.x - 2048;   // 0..31
        const int kt  = bt & 3;
        const int ct8 = bt >> 2;
        __shared__ float tile[32][33];
        const int rr = tid >> 5, cc = tid & 31;
        #pragma unroll
        for (int i = 0; i < 4; ++i)
            tile[rr + 8 * i][cc] = W[(size_t)(kt * 32 + rr + 8 * i) * 256 + ct8 * 32 + cc];
        __syncthreads();
        #pragma unroll
        for (int i = 0; i < 4; ++i)
            WT[(size_t)(ct8 * 32 + rr + 8 * i) * FIN + kt * 32 + cc] = f2bf(tile[cc][rr + 8 * i]);
    }
}

// h = x@W in MFMA fragment-major layout + ei/ej (log2e-scaled). grid (nb=32, b=4), wave=head.
__global__ __launch_bounds__(256)
void k_gemm_h(const float* __restrict__ x, const u16* __restrict__ WT,
              const float* __restrict__ a,
              u16* __restrict__ hTf, float* __restrict__ ei_g, float* __restrict__ ej_g) {
    const int nb = blockIdx.x, b = blockIdx.y;
    const int tid = threadIdx.x, hd = tid >> 6, lane = tid & 63, ln15 = lane & 15, q = lane >> 4;
    const int q8 = q * 8;
    const int n0 = nb * 64;

    __shared__ u16 xs[64][136];
    __shared__ float cs[NH][4][16][20];   // [hd][nt][row][col+pad], reused per ct (same-wave)
    {
        const int col = (tid & 31) * 4;
        const int r0  = tid >> 5;
        #pragma unroll
        for (int rr = 0; rr < 8; ++rr) {
            const int row = r0 + rr * 8;
            const float4 v = *(const float4*)(x + ((size_t)(b * NN + n0 + row)) * FIN + col);
            *(u32*)&xs[row][col]     = pk_bf(v.x, v.y);
            *(u32*)&xs[row][col + 2] = pk_bf(v.z, v.w);
        }
    }
    __syncthreads();

    int irow[4], icol[4];
    cd_probe(ln15, q, irow, icol);

    f32x4 acc[4][4] = {};                // [ct][nt]
    #pragma unroll
    for (int ks = 0; ks < 4; ++ks) {
        sh8 af[4], bfr[4];
        #pragma unroll
        for (int ct = 0; ct < 4; ++ct)
            af[ct] = *(const sh8*)(WT + (size_t)(hd * 64 + ct * 16 + ln15) * FIN + ks * 32 + q8);
        #pragma unroll
        for (int nt = 0; nt < 4; ++nt)
            bfr[nt] = *(const sh8*)&xs[nt * 16 + ln15][ks * 32 + q8];
        #pragma unroll
        for (int ct = 0; ct < 4; ++ct)
            #pragma unroll
            for (int nt = 0; nt < 4; ++nt)
                acc[ct][nt] = __builtin_amdgcn_mfma_f32_16x16x32_bf16(af[ct], bfr[nt], acc[ct][nt], 0, 0, 0);
    }

    float eip[4] = {}, ejq[4] = {};
    #pragma unroll
    for (int ct = 0; ct < 4; ++ct) {
        // canonicalize this ct through LDS (same-wave: no barrier needed)
        #pragma unroll
        for (int nt = 0; nt < 4; ++nt)
            #pragma unroll
            for (int r = 0; r < 4; ++r)
                cs[hd][nt][irow[r]][icol[r]] = acc[ct][nt][r];

        // fragment-major hTf write: lane (ln15,q) holds d=ct*16+ln15, j=n0+p*32+q*8+i
        #pragma unroll
        for (int p = 0; p < 2; ++p) {
            const float4 c0 = *(const float4*)&cs[hd][2 * p + (q >> 1)][ln15][(q & 1) * 8];
            const float4 c1 = *(const float4*)&cs[hd][2 * p + (q >> 1)][ln15][(q & 1) * 8 + 4];
            uint4 o;
            o.x = pk_bf(c0.x, c0.y); o.y = pk_bf(c0.z, c0.w);
            o.z = pk_bf(c1.x, c1.y); o.w = pk_bf(c1.z, c1.w);
            *(uint4*)(hTf + ((((size_t)(b * NH + hd) * 64 + nb * 2 + p) * 4 + ct) * 512) + lane * 8) = o;
        }

        // ei/ej partial sums (canonical reads)
        float a1v[4], a2v[4];
        #pragma unroll
        for (int r = 0; r < 4; ++r) {
            const int d = ct * 16 + 4 * q + r;
            a1v[r] = a[d] * LOG2E;
            a2v[r] = a[64 + d] * LOG2E;
        }
        #pragma unroll
        for (int nt = 0; nt < 4; ++nt)
            #pragma unroll
            for (int r = 0; r < 4; ++r) {
                const float v = cs[hd][nt][4 * q + r][ln15];
                eip[nt] += v * a1v[r];
                ejq[nt] += v * a2v[r];
            }
    }
    #pragma unroll
    for (int nt = 0; nt < 4; ++nt) {
        eip[nt] += __shfl_xor(eip[nt], 16);
        eip[nt] += __shfl_xor(eip[nt], 32);
        ejq[nt] += __shfl_xor(ejq[nt], 16);
        ejq[nt] += __shfl_xor(ejq[nt], 32);
    }
    if (lane < 16) {
        const size_t bhd = (size_t)(b * NH + hd) * NN;
        #pragma unroll
        for (int nt = 0; nt < 4; ++nt) {
            ei_g[bhd + n0 + nt * 16 + lane] = eip[nt];
            ej_g[bhd + n0 + nt * 16 + lane] = ejq[nt];
        }
    }
}

// grid (ib=64, js, b=4), block 256 (wave = head). h loads fully coalesced (1024B/wave).
__global__ __launch_bounds__(256, 3)
void k_attn(const u32* __restrict__ msk, const u16* __restrict__ hTf,
            const float* __restrict__ ei_g, const float* __restrict__ ej_g,
            float* __restrict__ o_part, float* __restrict__ l_part, int nj) {
    const int ib = blockIdx.x, js = blockIdx.y, b = blockIdx.z;
    const int js_n = gridDim.y;
    const int tid = threadIdx.x, hd = tid >> 6, lane = tid & 63, ln15 = lane & 15, q = lane >> 4;
    const int q8 = q * 8;
    const int iA = ib * 32 + ln15;

    int irow[4], icol[4];
    cd_probe(ln15, q, irow, icol);

    const size_t bhd = (size_t)(b * NH + hd) * NN;
    const float eivA = ei_g[bhd + iA];
    const float eivB = ei_g[bhd + iA + 16];
    const u32*   mptr = msk + (size_t)(b * 64) * NN;
    const float* ejp  = ej_g + bhd + q8;
    const u16*   hfp  = hTf + (size_t)(b * NH + hd) * (64 * 2048) + (size_t)lane * 8;

    sh8 ones;
    #pragma unroll
    for (int ii = 0; ii < 8; ++ii) ones[ii] = (short)0x3F80;

    f32x4 acc[8] = {};
    f32x4 accl[2] = {};

    const int jt0 = js * nj;
    u32 mA = mptr[(size_t)jt0 * NN + iA];
    u32 mB = mptr[(size_t)jt0 * NN + iA + 16];
    float4 e0 = *(const float4*)(ejp + jt0 * 32);
    float4 e1 = *(const float4*)(ejp + jt0 * 32 + 4);
    sh8 h0 = *(const sh8*)(hfp + (size_t)jt0 * 2048);
    sh8 h1 = *(const sh8*)(hfp + (size_t)jt0 * 2048 + 512);
    sh8 h2 = *(const sh8*)(hfp + (size_t)jt0 * 2048 + 1024);
    sh8 h3 = *(const sh8*)(hfp + (size_t)jt0 * 2048 + 1536);

    for (int t = 0; t < nj; ++t) {
        const int tn = (t + 1 < nj) ? jt0 + t + 1 : jt0;
        const u32 mAn = mptr[(size_t)tn * NN + iA];
        const u32 mBn = mptr[(size_t)tn * NN + iA + 16];
        const float4 e0n = *(const float4*)(ejp + tn * 32);
        const float4 e1n = *(const float4*)(ejp + tn * 32 + 4);
        const sh8 h0n = *(const sh8*)(hfp + (size_t)tn * 2048);
        const sh8 h1n = *(const sh8*)(hfp + (size_t)tn * 2048 + 512);
        const sh8 h2n = *(const sh8*)(hfp + (size_t)tn * 2048 + 1024);
        const sh8 h3n = *(const sh8*)(hfp + (size_t)tn * 2048 + 1536);

        const float ef[8] = { e0.x, e0.y, e0.z, e0.w, e1.x, e1.y, e1.z, e1.w };
        const u32 mqA = mA >> q8;
        const u32 mqB = mB >> q8;
        float pA[8], pB[8];
        #pragma unroll
        for (int ii = 0; ii < 8; ++ii) {
            float eA = eivA + ef[ii];
            float eB = eivB + ef[ii];
            eA = fmaxf(eA, 0.2f * eA);
            eB = fmaxf(eB, 0.2f * eB);
            const float xA = fast_exp2(eA);
            const float xB = fast_exp2(eB);
            pA[ii] = (mqA & (1u << ii)) ? xA : 0.f;
            pB[ii] = (mqB & (1u << ii)) ? xB : 0.f;
        }
        union { uint4 u; sh8 v; } avA, avB;
        avA.u.x = pk_bf(pA[0], pA[1]); avA.u.y = pk_bf(pA[2], pA[3]);
        avA.u.z = pk_bf(pA[4], pA[5]); avA.u.w = pk_bf(pA[6], pA[7]);
        avB.u.x = pk_bf(pB[0], pB[1]); avB.u.y = pk_bf(pB[2], pB[3]);
        avB.u.z = pk_bf(pB[4], pB[5]); avB.u.w = pk_bf(pB[6], pB[7]);

        acc[0] = __builtin_amdgcn_mfma_f32_16x16x32_bf16(avA.v, h0, acc[0], 0, 0, 0);
        acc[1] = __builtin_amdgcn_mfma_f32_16x16x32_bf16(avA.v, h1, acc[1], 0, 0, 0);
        acc[2] = __builtin_amdgcn_mfma_f32_16x16x32_bf16(avA.v, h2, acc[2], 0, 0, 0);
        acc[3] = __builtin_amdgcn_mfma_f32_16x16x32_bf16(avA.v, h3, acc[3], 0, 0, 0);
        accl[0] = __builtin_amdgcn_mfma_f32_16x16x32_bf16(avA.v, ones, accl[0], 0, 0, 0);
        acc[4] = __builtin_amdgcn_mfma_f32_16x16x32_bf16(avB.v, h0, acc[4], 0, 0, 0);
        acc[5] = __builtin_amdgcn_mfma_f32_16x16x32_bf16(avB.v, h1, acc[5], 0, 0, 0);
        acc[6] = __builtin_amdgcn_mfma_f32_16x16x32_bf16(avB.v, h2, acc[6], 0, 0, 0);
        acc[7] = __builtin_amdgcn_mfma_f32_16x16x32_bf16(avB.v, h3, acc[7], 0, 0, 0);
        accl[1] = __builtin_amdgcn_mfma_f32_16x16x32_bf16(avB.v, ones, accl[1], 0, 0, 0);

        mA = mAn; mB = mBn; e0 = e0n; e1 = e1n;
        h0 = h0n; h1 = h1n; h2 = h2n; h3 = h3n;
    }

    const size_t pbA = (((size_t)b * 128 + ib * 2 + 0) * js_n + js) * NH + hd;
    const size_t pbB = (((size_t)b * 128 + ib * 2 + 1) * js_n + js) * NH + hd;
    #pragma unroll
    for (int r = 0; r < 4; ++r) {
        l_part[pbA * 16 + irow[r]] = accl[0][r];
        l_part[pbB * 16 + irow[r]] = accl[1][r];
    }
    float* opA = o_part + pbA * 1024;
    float* opB = o_part + pbB * 1024;
    #pragma unroll
    for (int dt = 0; dt < 4; ++dt)
        #pragma unroll
        for (int r = 0; r < 4; ++r) {
            opA[(size_t)irow[r] * 64 + dt * 16 + icol[r]] = acc[dt][r];
            opB[(size_t)irow[r] * 64 + dt * 16 + icol[r]] = acc[4 + dt][r];
        }
}

template <int JS>
__global__ __launch_bounds__(256)
void k_combine(const float* __restrict__ o_part, const float* __restrict__ l_part,
               float* __restrict__ out) {
    const int ib = blockIdx.x, b = blockIdx.y;
    const int tid = threadIdx.x;
    const int i = tid >> 4, d4 = (tid & 15) * 4;
    float  lv[NH][JS];
    float4 ov[NH][JS];
    #pragma unroll
    for (int h = 0; h < NH; ++h)
        #pragma unroll
        for (int js = 0; js < JS; ++js) {
            const size_t pbase = (((size_t)b * 128 + ib) * JS + js) * NH + h;
            lv[h][js] = l_part[pbase * 16 + i];
            ov[h][js] = *(const float4*)(o_part + pbase * 1024 + (size_t)i * 64 + d4);
        }
    float4 sacc = {0.f, 0.f, 0.f, 0.f};
    #pragma unroll
    for (int h = 0; h < NH; ++h) {
        float l = 0.f;
        float4 oh = {0.f, 0.f, 0.f, 0.f};
        #pragma unroll
        for (int js = 0; js < JS; ++js) {
            l += lv[h][js];
            oh.x += ov[h][js].x; oh.y += ov[h][js].y;
            oh.z += ov[h][js].z; oh.w += ov[h][js].w;
        }
        const float inv = 0.25f / l;
        sacc.x += oh.x * inv; sacc.y += oh.y * inv;
        sacc.z += oh.z * inv; sacc.w += oh.w * inv;
    }
    *(float4*)(out + ((size_t)(b * NN) + ib * 16 + i) * DD + d4) = sacc;
}

extern "C" void kernel_launch(void* const* d_in, const int* in_sizes, int n_in,
                              void* d_out, int out_size, void* d_ws, size_t ws_size,
                              hipStream_t stream) {
    const float* x = nullptr; const int* adj = nullptr;
    const float* W = nullptr; const float* a = nullptr;
    for (int i = 0; i < n_in; ++i) {
        switch (in_sizes[i]) {
            case NB * NN * FIN:  x   = (const float*)d_in[i]; break;
            case NB * NN * NN:   adj = (const int*)d_in[i];   break;
            case FIN * 256:      W   = (const float*)d_in[i]; break;
            case 2 * DD:         a   = (const float*)d_in[i]; break;
            default: break;
        }
    }
    if (!x)   x   = (const float*)d_in[0];
    if (!adj) adj = (const int*)d_in[1];
    if (!W)   W   = (const float*)d_in[2];
    if (!a)   a   = (const float*)d_in[3];
    float* out = (float*)d_out;

    char* ws = (char*)d_ws;
    u16*   WT  = (u16*)(ws);
    float* ei  = (float*)(ws + 65536);
    float* ej  = (float*)(ws + 196608);
    u16*   hTf = (u16*)(ws + 327680);
    u32*   msk = (u32*)(ws + 4521984);
    float* l_p = (float*)(ws + 6619136);
    float* o_p = (float*)(ws + 7143424);

    const size_t need4 = 7143424 + (size_t)4 * 8388608;
    const size_t need2 = 7143424 + (size_t)2 * 8388608;
    const int js_n = (ws_size >= need4) ? 4 : (ws_size >= need2) ? 2 : 1;

    k_pack<<<dim3(2080), dim3(256), 0, stream>>>(adj, W, msk, WT);
    k_gemm_h<<<dim3(32, NB), dim3(256), 0, stream>>>(x, WT, a, hTf, ei, ej);
    k_attn<<<dim3(64, js_n, NB), dim3(256), 0, stream>>>(msk, hTf, ei, ej, o_p, l_p, 64 / js_n);
    if (js_n == 4)      k_combine<4><<<dim3(128, NB), dim3(256), 0, stream>>>(o_p, l_p, out);
    else if (js_n == 2) k_combine<2><<<dim3(128, NB), dim3(256), 0, stream>>>(o_p, l_p, out);
    else                k_combine<1><<<dim3(128, NB), dim3(256), 0, stream>>>(o_p, l_p, out);
}